// Round 1
// baseline (3219.508 us; speedup 1.0000x reference)
//
#include <hip/hip_runtime.h>
#include <cstdint>
#include <cstddef>

#define S_DIM 12
#define N_NODE 50000
#define N_PAD 50048
#define N_P2 50176
#define D_IN 64
#define D_H 128
#define N_E 600000
#define K_TOT 576   // 384 (h|t1h|t2h) + 192 (x|t1x|t2x)
#define N_COL 512   // 4 gates x 128
#define HID_P 80    // 65 padded to 80
#define N_HID 65

typedef short bf16x8 __attribute__((ext_vector_type(8)));
typedef float f32x4 __attribute__((ext_vector_type(4)));

__device__ __forceinline__ float bf2f(unsigned short u){
  union { unsigned int i; float f; } v; v.i = ((unsigned int)u) << 16; return v.f;
}
__device__ __forceinline__ unsigned short f2bf(float f){
  union { float f; unsigned int i; } v; v.f = f;
  unsigned int x = v.i;
  return (unsigned short)((x + 0x7fffu + ((x >> 16) & 1u)) >> 16);
}
__device__ __forceinline__ float sigf(float x){ return 1.f/(1.f + __expf(-x)); }

__device__ __forceinline__ void gload16(const void* g, void* lds){
  __builtin_amdgcn_global_load_lds((const __attribute__((address_space(1))) unsigned int*)g,
                                   (__attribute__((address_space(3))) unsigned int*)lds, 16, 0, 0);
}

// ---------------- prep: pack weights ----------------
// Bct[col][k] bf16 : col = g*128+d (gate-major), k in [0,576)
//   k<384 : Wh[g][k>>7][k&127][d];  k>=384 : Wx[g][(k-384)>>6][(k-384)&63][d]
__global__ void k_prep(const float* __restrict__ Wx, const float* __restrict__ Wh,
                       const float* __restrict__ bx, const float* __restrict__ bh,
                       const float* __restrict__ bg, const float* __restrict__ W1,
                       const float* __restrict__ b1, const float* __restrict__ W2,
                       unsigned short* __restrict__ Bct, float* __restrict__ btot,
                       unsigned short* __restrict__ W1t, float* __restrict__ b1p,
                       float* __restrict__ W2p)
{
  int idx = blockIdx.x*256 + threadIdx.x;
  if (idx < N_COL*K_TOT){
    int c = idx / K_TOT, k = idx - c*K_TOT;
    int g = c >> 7, d = c & 127;
    float v;
    if (k < 384){ int kt = k >> 7, j = k & 127; v = Wh[(((size_t)(g*3+kt))*128 + j)*128 + d]; }
    else { int kk = k - 384; int kt = kk >> 6, j = kk & 63; v = Wx[(((size_t)(g*3+kt))*64 + j)*128 + d]; }
    Bct[(size_t)c*K_TOT + k] = f2bf(v);
  }
  if (idx < N_COL) btot[idx] = bx[idx] + bh[idx] + bg[idx];
  if (idx < HID_P*D_H){ int c = idx >> 7, k = idx & 127;
    W1t[idx] = (c < N_HID) ? f2bf(W1[k*N_HID + c]) : (unsigned short)0; }
  if (idx < HID_P) b1p[idx] = (idx < N_HID) ? b1[idx] : 0.f;
  if (idx < HID_P*2){ int c = idx >> 1, j = idx & 1; W2p[idx] = (c < N_HID) ? W2[c*2 + j] : 0.f; }
}

// ---------------- graph preprocessing ----------------
__global__ void k_deg(const int* __restrict__ ei, int* __restrict__ dsrc, int* __restrict__ ddst){
  int e = blockIdx.x*256 + threadIdx.x;
  if (e < N_E){
    atomicAdd(&dsrc[ei[e]], 1);
    atomicAdd(&ddst[ei[N_E + e]], 1);
  }
}
__global__ void k_dinv(const int* __restrict__ dsrc, float* __restrict__ dinv){
  int n = blockIdx.x*256 + threadIdx.x;
  if (n < N_P2) dinv[n] = (dsrc[n] > 0) ? rsqrtf((float)dsrc[n]) : 0.f;
}
__global__ void k_scan1(const int* __restrict__ in, int* __restrict__ outp, int* __restrict__ part){
  __shared__ int sm[256];
  int tid = threadIdx.x;
  int i = blockIdx.x*256 + tid;
  int v = in[i];
  int x = v;
  sm[tid] = x; __syncthreads();
  for (int off=1; off<256; off<<=1){
    int y = (tid >= off) ? sm[tid-off] : 0;
    __syncthreads();
    x += y; sm[tid] = x; __syncthreads();
  }
  outp[i] = x - v;
  if (tid == 255) part[blockIdx.x] = x;
}
__global__ void k_scan2(int* __restrict__ part, int nblk){
  __shared__ int sm[256];
  int tid = threadIdx.x;
  int v = (tid < nblk) ? part[tid] : 0;
  int x = v; sm[tid] = x; __syncthreads();
  for (int off=1; off<256; off<<=1){
    int y = (tid >= off) ? sm[tid-off] : 0;
    __syncthreads();
    x += y; sm[tid] = x; __syncthreads();
  }
  if (tid < nblk) part[tid] = x - v;
}
__global__ void k_scan3(const int* __restrict__ outp, const int* __restrict__ part, int* __restrict__ offs){
  int i = blockIdx.x*256 + threadIdx.x;
  offs[i] = outp[i] + part[blockIdx.x];
}
__global__ void k_csr(const int* __restrict__ ei, const float* __restrict__ dinv,
                      const int* __restrict__ offs, int* __restrict__ cursor,
                      int* __restrict__ csrc, float* __restrict__ cwv){
  int e = blockIdx.x*256 + threadIdx.x;
  if (e < N_E){
    int s = ei[e], d = ei[N_E + e];
    int pos = atomicAdd(&cursor[d], 1);
    int q = offs[d] + pos;
    csrc[q] = s;
    cwv[q] = -dinv[s]*dinv[d];
  }
}

// ---------------- SpMM: one wave per node ----------------
// spmm1: t1h = L@h  -> Arec[:,128:256];  x_bf -> Ax[:,0:64]; t1x = L@x -> Ax[:,64:128]
__global__ void k_spmm1(unsigned short* __restrict__ Arec, const float* __restrict__ Ht,
                        unsigned short* __restrict__ Ax,
                        const int* __restrict__ offs, const int* __restrict__ csrc,
                        const float* __restrict__ cwv)
{
  int n = blockIdx.x*4 + (threadIdx.x >> 6);
  int l = threadIdx.x & 63;
  if (n >= N_NODE) return;
  int beg = offs[n], end = offs[n+1];
  float a0 = 0.f, a1 = 0.f, axv = 0.f;
  for (int q = beg; q < end; ++q){
    int s = csrc[q]; float w = cwv[q];
    unsigned int hv = *(const unsigned int*)(Arec + (size_t)s*384 + 2*l);
    a0  += w * bf2f((unsigned short)(hv & 0xffffu));
    a1  += w * bf2f((unsigned short)(hv >> 16));
    axv += w * Ht[(size_t)s*64 + l];
  }
  unsigned int o = ((unsigned int)f2bf(a1) << 16) | (unsigned int)f2bf(a0);
  *(unsigned int*)(Arec + (size_t)n*384 + 128 + 2*l) = o;
  Ax[(size_t)n*192 + 64 + l] = f2bf(axv);
  Ax[(size_t)n*192 + l]      = f2bf(Ht[(size_t)n*64 + l]);
}
// spmm2: t2h = 2*L@t1h - h -> Arec[:,256:384];  t2x = 2*L@t1x - x -> Ax[:,128:192]
__global__ void k_spmm2(unsigned short* __restrict__ Arec, unsigned short* __restrict__ Ax,
                        const int* __restrict__ offs, const int* __restrict__ csrc,
                        const float* __restrict__ cwv)
{
  int n = blockIdx.x*4 + (threadIdx.x >> 6);
  int l = threadIdx.x & 63;
  if (n >= N_NODE) return;
  int beg = offs[n], end = offs[n+1];
  float a0 = 0.f, a1 = 0.f, axv = 0.f;
  for (int q = beg; q < end; ++q){
    int s = csrc[q]; float w = cwv[q];
    unsigned int hv = *(const unsigned int*)(Arec + (size_t)s*384 + 128 + 2*l);
    a0  += w * bf2f((unsigned short)(hv & 0xffffu));
    a1  += w * bf2f((unsigned short)(hv >> 16));
    axv += w * bf2f(Ax[(size_t)s*192 + 64 + l]);
  }
  unsigned int h0 = *(const unsigned int*)(Arec + (size_t)n*384 + 2*l);
  float t20 = 2.f*a0 - bf2f((unsigned short)(h0 & 0xffffu));
  float t21 = 2.f*a1 - bf2f((unsigned short)(h0 >> 16));
  unsigned int o = ((unsigned int)f2bf(t21) << 16) | (unsigned int)f2bf(t20);
  *(unsigned int*)(Arec + (size_t)n*384 + 256 + 2*l) = o;
  float xo = bf2f(Ax[(size_t)n*192 + l]);
  Ax[(size_t)n*192 + 128 + l] = f2bf(2.f*axv - xo);
}

// ---------------- GEMM: Z[N_PAD,512] = [Arec | Ax] @ Bct^T, bf16 MFMA ----------------
// 128x128 tile, 4 waves, wave = 64x64, K-iter = 64, m97-style 2-barrier loop.
__global__ __launch_bounds__(256,2) void k_gemm(const unsigned short* __restrict__ Arec,
                                                const unsigned short* __restrict__ Ax,
                                                const unsigned short* __restrict__ Bct,
                                                float* __restrict__ Z)
{
  __shared__ __align__(16) unsigned short As[128*64]; // [row][k]
  __shared__ __align__(16) unsigned short Bs[128*64]; // [col][k]
  int tid = threadIdx.x;
  int w = tid >> 6, l = tid & 63;
  int n0 = blockIdx.x * 128;
  int m0 = blockIdx.y * 128;
  const f32x4 vzero = {0.f,0.f,0.f,0.f};
  f32x4 acc[4][4];
#pragma unroll
  for (int i=0;i<4;++i)
#pragma unroll
    for (int j=0;j<4;++j) acc[i][j] = vzero;
  int wr = w >> 1, wn = w & 1;
  for (int it=0; it<9; ++it){
    const unsigned short* Ab; int astr, acol;
    if (it < 6){ Ab = Arec; astr = 384; acol = it*64; }
    else       { Ab = Ax;   astr = 192; acol = (it-6)*64; }
    if (it) __syncthreads();
#pragma unroll
    for (int i=0;i<4;++i){
      int rr = w*32 + i*8;
      int row = rr + (l>>3);
      gload16(Ab  + (size_t)(m0+row)*astr + acol + (l&7)*8, (void*)(As + rr*64));
      gload16(Bct + (size_t)(n0+row)*K_TOT + it*64 + (l&7)*8, (void*)(Bs + rr*64));
    }
    __syncthreads();
#pragma unroll
    for (int kk=0; kk<2; ++kk){
      bf16x8 af[4], bfv[4];
#pragma unroll
      for (int i=0;i<4;++i) af[i]  = *(const bf16x8*)(As + (wr*64 + i*16 + (l&15))*64 + kk*32 + (l>>4)*8);
#pragma unroll
      for (int j=0;j<4;++j) bfv[j] = *(const bf16x8*)(Bs + (wn*64 + j*16 + (l&15))*64 + kk*32 + (l>>4)*8);
#pragma unroll
      for (int i=0;i<4;++i)
#pragma unroll
        for (int j=0;j<4;++j)
          acc[i][j] = __builtin_amdgcn_mfma_f32_16x16x32_bf16(af[i], bfv[j], acc[i][j], 0,0,0);
    }
  }
#pragma unroll
  for (int i=0;i<4;++i)
#pragma unroll
    for (int j=0;j<4;++j){
      int m = m0 + wr*64 + i*16 + (l>>4)*4;
      int n = n0 + wn*64 + j*16 + (l&15);
      float* zp = Z + (size_t)m*N_COL + n;
#pragma unroll
      for (int r=0;r<4;++r) zp[(size_t)r*N_COL] = acc[i][j][r];
    }
}

// ---------------- LSTM gates (peephole) ----------------
__global__ void k_gates(const float* __restrict__ Z, const float* __restrict__ btot,
                        const float* __restrict__ wc, float* __restrict__ c,
                        unsigned short* __restrict__ Arec)
{
  int idx = blockIdx.x*256 + threadIdx.x;   // n*128+d
  int n = idx >> 7, d = idx & 127;
  const float* zr = Z + (size_t)n*N_COL;
  float zi = zr[d]       + btot[d];
  float zf = zr[128 + d] + btot[128 + d];
  float zt = zr[256 + d] + btot[256 + d];
  float zo = zr[384 + d] + btot[384 + d];
  float co = c[idx];
  float gi = sigf(zi + wc[d]*co);
  float gf = sigf(zf + wc[128 + d]*co);
  float tt = tanhf(zt);
  float cn = gf*co + gi*tt;
  float go = sigf(zo + wc[256 + d]*cn);
  float h = go * tanhf(cn);
  c[idx] = cn;
  Arec[(size_t)n*384 + d] = f2bf(h);
}

// ---------------- tanh + LN + MLP + sigmoid + transpose (per step) ----------------
__global__ __launch_bounds__(256,2) void k_lnmlp(const unsigned short* __restrict__ Arec,
                        const unsigned short* __restrict__ W1t, const float* __restrict__ b1p,
                        const float* __restrict__ W2p, const float* __restrict__ b2,
                        const float* __restrict__ gam, const float* __restrict__ bet,
                        float* __restrict__ out, int t)
{
  __shared__ __align__(16) unsigned short xn[64*128];
  __shared__ __align__(16) unsigned short w1s[HID_P*128];
  __shared__ float w2s[HID_P*2];
  __shared__ float b1s[HID_P];
  __shared__ float b2s[2];
  int tid = threadIdx.x;
  for (int i = tid; i < HID_P*128/8; i += 256) ((int4*)w1s)[i] = ((const int4*)W1t)[i];
  if (tid < HID_P*2) w2s[tid] = W2p[tid];
  if (tid < HID_P)   b1s[tid] = b1p[tid];
  if (tid < 2)       b2s[tid] = b2[tid];
  int n0 = blockIdx.x*64;
  int row = tid >> 2, part = tid & 3;
  int n = n0 + row;
  float vals[32];
  float s = 0.f, ss = 0.f;
  if (n < N_NODE){
    const unsigned short* hp = Arec + (size_t)n*384 + part*32;
#pragma unroll
    for (int k=0;k<32;++k){
      float x = tanhf(bf2f(hp[k]));
      vals[k] = x; s += x; ss += x*x;
    }
  } else {
#pragma unroll
    for (int k=0;k<32;++k) vals[k] = 0.f;
  }
  s  += __shfl_xor(s,1);  s  += __shfl_xor(s,2);
  ss += __shfl_xor(ss,1); ss += __shfl_xor(ss,2);
  float mu = s * (1.f/128.f);
  float var = ss * (1.f/128.f) - mu*mu;
  float inv = rsqrtf(fmaxf(var, 0.f) + 1e-5f);
#pragma unroll
  for (int k=0;k<32;++k){
    int d = part*32 + k;
    xn[row*128 + d] = f2bf((vals[k]-mu)*inv*gam[d] + bet[d]);
  }
  __syncthreads();
  int w = tid >> 6, l = tid & 63;
  const f32x4 vzero = {0.f,0.f,0.f,0.f};
  f32x4 acc[5];
#pragma unroll
  for (int tj=0;tj<5;++tj) acc[tj] = vzero;
#pragma unroll
  for (int kk=0;kk<4;++kk){
    bf16x8 a = *(const bf16x8*)(xn + (w*16 + (l&15))*128 + kk*32 + (l>>4)*8);
#pragma unroll
    for (int tj=0;tj<5;++tj){
      bf16x8 b = *(const bf16x8*)(w1s + (tj*16 + (l&15))*128 + kk*32 + (l>>4)*8);
      acc[tj] = __builtin_amdgcn_mfma_f32_16x16x32_bf16(a, b, acc[tj], 0,0,0);
    }
  }
#pragma unroll
  for (int r=0;r<4;++r){
    int rn = n0 + w*16 + (l>>4)*4 + r;
    float p0 = 0.f, p1 = 0.f;
#pragma unroll
    for (int tj=0;tj<5;++tj){
      int col = tj*16 + (l&15);
      float hv = fmaxf(acc[tj][r] + b1s[col], 0.f);
      p0 += hv * w2s[col*2];
      p1 += hv * w2s[col*2+1];
    }
    p0 += __shfl_xor(p0,1); p0 += __shfl_xor(p0,2); p0 += __shfl_xor(p0,4); p0 += __shfl_xor(p0,8);
    p1 += __shfl_xor(p1,1); p1 += __shfl_xor(p1,2); p1 += __shfl_xor(p1,4); p1 += __shfl_xor(p1,8);
    if ((l & 15) == 0 && rn < N_NODE){
      float* op = out + (size_t)rn*24 + t;   // out[n][c][s], C=2, S=12
      op[0]  = sigf(p0 + b2s[0]);
      op[12] = sigf(p1 + b2s[1]);
    }
  }
}

extern "C" void kernel_launch(void* const* d_in, const int* in_sizes, int n_in,
                              void* d_out, int out_size, void* d_ws, size_t ws_size,
                              hipStream_t stream)
{
  const float* H   = (const float*)d_in[0];
  const int*   ei  = (const int*)d_in[1];
  const float* Wx  = (const float*)d_in[2];
  const float* bx  = (const float*)d_in[3];
  const float* Wh  = (const float*)d_in[4];
  const float* bh  = (const float*)d_in[5];
  const float* bg  = (const float*)d_in[6];
  const float* wc  = (const float*)d_in[7];
  const float* gam = (const float*)d_in[8];
  const float* bet = (const float*)d_in[9];
  const float* W1  = (const float*)d_in[10];
  const float* b1  = (const float*)d_in[11];
  const float* W2  = (const float*)d_in[12];
  const float* b2  = (const float*)d_in[13];
  float* out = (float*)d_out;
  (void)in_sizes; (void)n_in; (void)out_size; (void)ws_size;

  char* p = (char*)d_ws;
  auto alloc = [&](size_t bytes)->char*{ char* r = p; p += (bytes + 255) & ~(size_t)255; return r; };
  // ---- zeroed region (one memset) ----
  char* zbase = p;
  float*          c_st = (float*)alloc((size_t)N_PAD*128*4);
  unsigned short* Arec = (unsigned short*)alloc((size_t)N_PAD*384*2);
  unsigned short* Ax   = (unsigned short*)alloc((size_t)N_PAD*192*2);
  int* dsrc   = (int*)alloc((size_t)N_P2*4);
  int* ddst   = (int*)alloc((size_t)N_P2*4);
  int* cursor = (int*)alloc((size_t)N_P2*4);
  size_t zbytes = (size_t)(p - zbase);
  // ---- rest ----
  float*          Zb   = (float*)alloc((size_t)N_PAD*N_COL*4);
  unsigned short* Bct  = (unsigned short*)alloc((size_t)N_COL*K_TOT*2);
  float*          btot = (float*)alloc(N_COL*4);
  unsigned short* W1t  = (unsigned short*)alloc(HID_P*128*2);
  float*          b1p  = (float*)alloc(HID_P*4);
  float*          W2p  = (float*)alloc(HID_P*2*4);
  float*          dinv = (float*)alloc((size_t)N_P2*4);
  int*            offs = (int*)alloc((size_t)(N_P2+256)*4);
  int*            outp = (int*)alloc((size_t)N_P2*4);
  int*            partb= (int*)alloc(256*4);
  int*            csrc = (int*)alloc((size_t)N_E*4);
  float*          cwv  = (float*)alloc((size_t)N_E*4);

  hipMemsetAsync(zbase, 0, zbytes, stream);
  k_prep<<<(N_COL*K_TOT + 255)/256, 256, 0, stream>>>(Wx, Wh, bx, bh, bg, W1, b1, W2,
                                                      Bct, btot, W1t, b1p, W2p);
  k_deg<<<(N_E + 255)/256, 256, 0, stream>>>(ei, dsrc, ddst);
  k_dinv<<<N_P2/256, 256, 0, stream>>>(dsrc, dinv);
  k_scan1<<<N_P2/256, 256, 0, stream>>>(ddst, outp, partb);
  k_scan2<<<1, 256, 0, stream>>>(partb, N_P2/256);
  k_scan3<<<N_P2/256, 256, 0, stream>>>(outp, partb, offs);
  k_csr<<<(N_E + 255)/256, 256, 0, stream>>>(ei, dinv, offs, cursor, csrc, cwv);

  for (int t = 0; t < S_DIM; ++t){
    k_spmm1<<<N_NODE/4, 256, 0, stream>>>(Arec, H + (size_t)t*N_NODE*D_IN, Ax, offs, csrc, cwv);
    k_spmm2<<<N_NODE/4, 256, 0, stream>>>(Arec, Ax, offs, csrc, cwv);
    k_gemm<<<dim3(N_COL/128, N_PAD/128), 256, 0, stream>>>(Arec, Ax, Bct, Zb);
    k_gates<<<(N_NODE*128)/256, 256, 0, stream>>>(Zb, btot, wc, c_st, Arec);
    k_lnmlp<<<N_PAD/64, 256, 0, stream>>>(Arec, W1t, b1p, W2p, b2, gam, bet, out, t);
  }
}

// Round 2
// 3144.795 us; speedup vs baseline: 1.0238x; 1.0238x over previous
//
#include <hip/hip_runtime.h>
#include <cstdint>
#include <cstddef>

#define S_DIM 12
#define N_NODE 50000
#define N_PAD 50048
#define N_P2 50176
#define D_IN 64
#define D_H 128
#define N_E 600000
#define K_TOT 576   // 128 h + 256 (u1h|u2h) + 64 x + 128 (u1x|u2x)
#define N_COL 512   // 4 gates x 128, interleaved cc = (d&15) + 16*g + 64*(d>>4)
#define HID_P 80
#define N_HID 65

typedef short bf16x8 __attribute__((ext_vector_type(8)));
typedef float f32x4 __attribute__((ext_vector_type(4)));

__device__ __forceinline__ float bf2f(unsigned short u){
  union { unsigned int i; float f; } v; v.i = ((unsigned int)u) << 16; return v.f;
}
__device__ __forceinline__ unsigned short f2bf(float f){
  union { float f; unsigned int i; } v; v.f = f;
  unsigned int x = v.i;
  return (unsigned short)((x + 0x7fffu + ((x >> 16) & 1u)) >> 16);
}
__device__ __forceinline__ float sigf(float x){ return 1.f/(1.f + __expf(-x)); }
__device__ __forceinline__ float ftanh(float x){
  x = fminf(fmaxf(x, -12.f), 12.f);
  float e = __expf(2.f*x);
  return (e - 1.f)/(e + 1.f);
}

__device__ __forceinline__ void gload16(const void* g, void* lds){
  __builtin_amdgcn_global_load_lds((const __attribute__((address_space(1))) unsigned int*)g,
                                   (__attribute__((address_space(3))) unsigned int*)lds, 16, 0, 0);
}

// ---------------- prep: pack weights (gate-interleaved cols + Chebyshev fold) ----
// Bct[cc][k]: cc = (d&15)+16*g+64*(d>>4).  k-blocks: [0,128)=h*(W0-W2), [128,256)=u1h*W1,
// [256,384)=u2h*2W2, [384,448)=x*(Wx0-Wx2), [448,512)=u1x*Wx1, [512,576)=u2x*2Wx2
__global__ void k_prep(const float* __restrict__ Wx, const float* __restrict__ Wh,
                       const float* __restrict__ bx, const float* __restrict__ bh,
                       const float* __restrict__ bg, const float* __restrict__ W1,
                       const float* __restrict__ b1, const float* __restrict__ W2,
                       unsigned short* __restrict__ Bct, float* __restrict__ btot,
                       unsigned short* __restrict__ W1t, float* __restrict__ b1p,
                       float* __restrict__ W2p)
{
  int idx = blockIdx.x*256 + threadIdx.x;
  if (idx < N_COL*K_TOT){
    int cc = idx / K_TOT, k = idx - cc*K_TOT;
    int g = (cc>>4)&3, d = (cc&15) + ((cc>>6)<<4);
    float v;
    if (k < 384){
      int kt = k >> 7, j = k & 127;
      const float* Wg = Wh + (size_t)g*3*128*128;
      if (kt == 0)      v = Wg[(size_t)j*128 + d] - Wg[(size_t)(256+j)*128 + d];
      else if (kt == 1) v = Wg[(size_t)(128+j)*128 + d];
      else              v = 2.f*Wg[(size_t)(256+j)*128 + d];
    } else {
      int kk = k - 384; int kt = kk >> 6, j = kk & 63;
      const float* Wg = Wx + (size_t)g*3*64*128;
      if (kt == 0)      v = Wg[(size_t)j*128 + d] - Wg[(size_t)(128+j)*128 + d];
      else if (kt == 1) v = Wg[(size_t)(64+j)*128 + d];
      else              v = 2.f*Wg[(size_t)(128+j)*128 + d];
    }
    Bct[(size_t)cc*K_TOT + k] = f2bf(v);
  }
  if (idx < N_COL) btot[idx] = bx[idx] + bh[idx] + bg[idx];   // gate-major g*128+d
  if (idx < HID_P*D_H){ int c = idx >> 7, k = idx & 127;
    W1t[idx] = (c < N_HID) ? f2bf(W1[k*N_HID + c]) : (unsigned short)0; }
  if (idx < HID_P) b1p[idx] = (idx < N_HID) ? b1[idx] : 0.f;
  if (idx < HID_P*2){ int c = idx >> 1, j = idx & 1; W2p[idx] = (c < N_HID) ? W2[c*2 + j] : 0.f; }
}

// ---------------- H -> bf16 (all steps, padded rows zeroed) ----------------
__global__ void k_xcvt(const float* __restrict__ H, unsigned short* __restrict__ Xbf){
  long idx = (long)(blockIdx.x*256 + threadIdx.x)*8;   // over 12*N_PAD*64
  int t = (int)(idx / ((long)N_PAD*64));
  long rem = idx - (long)t*N_PAD*64;
  int n = (int)(rem >> 6), d = (int)(rem & 63);
  unsigned short o[8];
  if (n < N_NODE){
    const float* hp = H + ((size_t)t*N_NODE + n)*64 + d;
    float4 v0 = *(const float4*)hp, v1 = *(const float4*)(hp+4);
    o[0]=f2bf(v0.x); o[1]=f2bf(v0.y); o[2]=f2bf(v0.z); o[3]=f2bf(v0.w);
    o[4]=f2bf(v1.x); o[5]=f2bf(v1.y); o[6]=f2bf(v1.z); o[7]=f2bf(v1.w);
  } else {
    for (int i=0;i<8;++i) o[i]=0;
  }
  *(int4*)(Xbf + idx) = *(int4*)o;
}

// ---------------- graph preprocessing ----------------
__global__ void k_deg(const int* __restrict__ ei, int* __restrict__ dsrc, int* __restrict__ ddst){
  int e = blockIdx.x*256 + threadIdx.x;
  if (e < N_E){
    atomicAdd(&dsrc[ei[e]], 1);
    atomicAdd(&ddst[ei[N_E + e]], 1);
  }
}
__global__ void k_dinv(const int* __restrict__ dsrc, float* __restrict__ dinv){
  int n = blockIdx.x*256 + threadIdx.x;
  if (n < N_P2) dinv[n] = (dsrc[n] > 0) ? rsqrtf((float)dsrc[n]) : 0.f;
}
__global__ void k_scan1(const int* __restrict__ in, int* __restrict__ outp, int* __restrict__ part){
  __shared__ int sm[256];
  int tid = threadIdx.x;
  int i = blockIdx.x*256 + tid;
  int v = in[i];
  int x = v;
  sm[tid] = x; __syncthreads();
  for (int off=1; off<256; off<<=1){
    int y = (tid >= off) ? sm[tid-off] : 0;
    __syncthreads();
    x += y; sm[tid] = x; __syncthreads();
  }
  outp[i] = x - v;
  if (tid == 255) part[blockIdx.x] = x;
}
__global__ void k_scan2(int* __restrict__ part, int nblk){
  __shared__ int sm[256];
  int tid = threadIdx.x;
  int v = (tid < nblk) ? part[tid] : 0;
  int x = v; sm[tid] = x; __syncthreads();
  for (int off=1; off<256; off<<=1){
    int y = (tid >= off) ? sm[tid-off] : 0;
    __syncthreads();
    x += y; sm[tid] = x; __syncthreads();
  }
  if (tid < nblk) part[tid] = x - v;
}
__global__ void k_scan3(const int* __restrict__ outp, const int* __restrict__ part, int* __restrict__ offs){
  int i = blockIdx.x*256 + threadIdx.x;
  offs[i] = outp[i] + part[blockIdx.x];
}
__global__ void k_csr(const int* __restrict__ ei, const float* __restrict__ dinv,
                      const int* __restrict__ offs, int* __restrict__ cursor,
                      int2* __restrict__ cedge){
  int e = blockIdx.x*256 + threadIdx.x;
  if (e < N_E){
    int s = ei[e], d = ei[N_E + e];
    int pos = atomicAdd(&cursor[d], 1);
    float w = -dinv[s]*dinv[d];
    cedge[offs[d] + pos] = make_int2(s, __float_as_int(w));
  }
}

// ---------------- x-side spmm, all 12 steps, hoisted out of the loop ----------
// Axt[t][n][0:64] = u1x = (L x)[n], Axt[t][n][64:128] = u2x = (L u1x)[n]
__global__ void k_xspmm1(const unsigned short* __restrict__ Xbf, unsigned short* __restrict__ Axt,
                         const int* __restrict__ offs, const int2* __restrict__ cedge){
  int n = blockIdx.x*4 + (threadIdx.x >> 6);
  int l = threadIdx.x & 63;
  if (n >= N_NODE) return;
  int t = blockIdx.y*2 + (l >> 5);
  int dl = l & 31;
  const unsigned short* Xt = Xbf + (size_t)t*N_PAD*64;
  int beg = offs[n], end = offs[n+1];
  float a0 = 0.f, a1 = 0.f;
  for (int q = beg; q < end; ++q){
    int2 e = cedge[q]; float w = __int_as_float(e.y);
    unsigned int xv = *(const unsigned int*)(Xt + (size_t)e.x*64 + 2*dl);
    a0 += w*bf2f((unsigned short)(xv & 0xffffu));
    a1 += w*bf2f((unsigned short)(xv >> 16));
  }
  *(unsigned int*)(Axt + ((size_t)t*N_PAD + n)*128 + 2*dl) =
      ((unsigned int)f2bf(a1) << 16) | (unsigned int)f2bf(a0);
}
__global__ void k_xspmm2(unsigned short* __restrict__ Axt,
                         const int* __restrict__ offs, const int2* __restrict__ cedge){
  int n = blockIdx.x*4 + (threadIdx.x >> 6);
  int l = threadIdx.x & 63;
  if (n >= N_NODE) return;
  int t = blockIdx.y*2 + (l >> 5);
  int dl = l & 31;
  const unsigned short* At = Axt + (size_t)t*N_PAD*128;
  int beg = offs[n], end = offs[n+1];
  float a0 = 0.f, a1 = 0.f;
  for (int q = beg; q < end; ++q){
    int2 e = cedge[q]; float w = __int_as_float(e.y);
    unsigned int xv = *(const unsigned int*)(At + (size_t)e.x*128 + 2*dl);
    a0 += w*bf2f((unsigned short)(xv & 0xffffu));
    a1 += w*bf2f((unsigned short)(xv >> 16));
  }
  *(unsigned int*)(Axt + ((size_t)t*N_PAD + n)*128 + 64 + 2*dl) =
      ((unsigned int)f2bf(a1) << 16) | (unsigned int)f2bf(a0);
}

// ---------------- per-step h-side spmm ----------------
// U[n][0:128] = u1h = L h ; U[n][128:256] = u2h = L u1h
__global__ void k_spmm1(const unsigned short* __restrict__ Hc, unsigned short* __restrict__ U,
                        const int* __restrict__ offs, const int2* __restrict__ cedge){
  int n = blockIdx.x*4 + (threadIdx.x >> 6);
  int l = threadIdx.x & 63;
  if (n >= N_NODE) return;
  int beg = offs[n], end = offs[n+1];
  float a0 = 0.f, a1 = 0.f;
  for (int q = beg; q < end; ++q){
    int2 e = cedge[q]; float w = __int_as_float(e.y);
    unsigned int hv = *(const unsigned int*)(Hc + (size_t)e.x*128 + 2*l);
    a0 += w*bf2f((unsigned short)(hv & 0xffffu));
    a1 += w*bf2f((unsigned short)(hv >> 16));
  }
  *(unsigned int*)(U + (size_t)n*256 + 2*l) =
      ((unsigned int)f2bf(a1) << 16) | (unsigned int)f2bf(a0);
}
__global__ void k_spmm2(unsigned short* __restrict__ U,
                        const int* __restrict__ offs, const int2* __restrict__ cedge){
  int n = blockIdx.x*4 + (threadIdx.x >> 6);
  int l = threadIdx.x & 63;
  if (n >= N_NODE) return;
  int beg = offs[n], end = offs[n+1];
  float a0 = 0.f, a1 = 0.f;
  for (int q = beg; q < end; ++q){
    int2 e = cedge[q]; float w = __int_as_float(e.y);
    unsigned int hv = *(const unsigned int*)(U + (size_t)e.x*256 + 2*l);
    a0 += w*bf2f((unsigned short)(hv & 0xffffu));
    a1 += w*bf2f((unsigned short)(hv >> 16));
  }
  *(unsigned int*)(U + (size_t)n*256 + 128 + 2*l) =
      ((unsigned int)f2bf(a1) << 16) | (unsigned int)f2bf(a0);
}

// ---------------- fused GEMM + LSTM gates ----------------
// Z = [h|u1h|u2h|x|u1x|u2x] @ Bct^T; gate-interleaved cols => frag j == gate.
// Epilogue computes i,f,t,o -> c_new, h_new entirely in registers.
__global__ __launch_bounds__(256,2) void k_gemm(
    const unsigned short* __restrict__ Hc, const unsigned short* __restrict__ U,
    const unsigned short* __restrict__ Xt, const unsigned short* __restrict__ Axt,
    const unsigned short* __restrict__ Bct, const float* __restrict__ btot,
    const float* __restrict__ wc, float* __restrict__ c, unsigned short* __restrict__ Hn)
{
  __shared__ __align__(16) unsigned short As[128*64];
  __shared__ __align__(16) unsigned short Bs[128*64];
  int tid = threadIdx.x;
  int w = tid >> 6, l = tid & 63;
  // bijective XCD-chunked swizzle (nwg = 4*391 = 1564)
  const int NWG = 1564, q8 = NWG >> 3, r8 = NWG & 7;
  int L = blockIdx.y*4 + blockIdx.x;
  int xcd = L & 7, li = L >> 3;
  int W = (xcd < r8 ? xcd*(q8+1) : r8*(q8+1) + (xcd-r8)*q8) + li;
  int bx = W & 3, by = W >> 2;
  int n0 = bx * 128;
  int m0 = by * 128;
  const f32x4 vzero = {0.f,0.f,0.f,0.f};
  f32x4 acc[4][4];
#pragma unroll
  for (int i=0;i<4;++i)
#pragma unroll
    for (int j=0;j<4;++j) acc[i][j] = vzero;
  int wr = w >> 1, wn = w & 1;
  for (int it=0; it<9; ++it){
    const unsigned short* Ab; int astr, acol;
    if (it < 2)      { Ab = Hc;  astr = 128; acol = it*64; }
    else if (it < 6) { Ab = U;   astr = 256; acol = (it-2)*64; }
    else if (it == 6){ Ab = Xt;  astr = 64;  acol = 0; }
    else             { Ab = Axt; astr = 128; acol = (it-7)*64; }
    if (it) __syncthreads();
#pragma unroll
    for (int i=0;i<4;++i){
      int rr = w*32 + i*8;
      int row = rr + (l>>3);
      gload16(Ab  + (size_t)(m0+row)*astr + acol + (l&7)*8, (void*)(As + rr*64));
      gload16(Bct + (size_t)(n0+row)*K_TOT + it*64 + (l&7)*8, (void*)(Bs + rr*64));
    }
    __syncthreads();
#pragma unroll
    for (int kk=0; kk<2; ++kk){
      bf16x8 af[4], bfv[4];
#pragma unroll
      for (int i=0;i<4;++i) af[i]  = *(const bf16x8*)(As + (wr*64 + i*16 + (l&15))*64 + kk*32 + (l>>4)*8);
#pragma unroll
      for (int j=0;j<4;++j) bfv[j] = *(const bf16x8*)(Bs + (wn*64 + j*16 + (l&15))*64 + kk*32 + (l>>4)*8);
#pragma unroll
      for (int i=0;i<4;++i)
#pragma unroll
        for (int j=0;j<4;++j)
          acc[i][j] = __builtin_amdgcn_mfma_f32_16x16x32_bf16(af[i], bfv[j], acc[i][j], 0,0,0);
    }
  }
  // ---- fused gate epilogue: frag j is gate j, d = 16*(2*bx+wn) + (l&15) ----
  int dd = (((bx<<1) + wn) << 4) | (l & 15);
  float b_i = btot[dd], b_f = btot[128+dd], b_t = btot[256+dd], b_o = btot[384+dd];
  float wci = wc[dd], wcf = wc[128+dd], wco = wc[256+dd];
#pragma unroll
  for (int i=0;i<4;++i){
    int row0 = m0 + wr*64 + i*16 + (l>>4)*4;
#pragma unroll
    for (int r=0;r<4;++r){
      int row = row0 + r;
      float co = c[(size_t)row*128 + dd];
      float gi = sigf(acc[i][0][r] + b_i + wci*co);
      float gf = sigf(acc[i][1][r] + b_f + wcf*co);
      float tt = ftanh(acc[i][2][r] + b_t);
      float cn = gf*co + gi*tt;
      float go = sigf(acc[i][3][r] + b_o + wco*cn);
      float h = go * ftanh(cn);
      c[(size_t)row*128 + dd] = cn;
      Hn[(size_t)row*128 + dd] = f2bf(h);
    }
  }
}

// ---------------- tanh + LN + MLP + sigmoid + transpose (per step) ----------------
__global__ __launch_bounds__(256,2) void k_lnmlp(const unsigned short* __restrict__ Hn,
                        const unsigned short* __restrict__ W1t, const float* __restrict__ b1p,
                        const float* __restrict__ W2p, const float* __restrict__ b2,
                        const float* __restrict__ gam, const float* __restrict__ bet,
                        float* __restrict__ out, int t)
{
  __shared__ __align__(16) unsigned short xn[64*128];
  __shared__ __align__(16) unsigned short w1s[HID_P*128];
  __shared__ float w2s[HID_P*2];
  __shared__ float b1s[HID_P];
  __shared__ float b2s[2];
  int tid = threadIdx.x;
  for (int i = tid; i < HID_P*128/8; i += 256) ((int4*)w1s)[i] = ((const int4*)W1t)[i];
  if (tid < HID_P*2) w2s[tid] = W2p[tid];
  if (tid < HID_P)   b1s[tid] = b1p[tid];
  if (tid < 2)       b2s[tid] = b2[tid];
  int n0 = blockIdx.x*64;
  int row = tid >> 2, part = tid & 3;
  int n = n0 + row;
  float vals[32];
  float s = 0.f, ss = 0.f;
  if (n < N_NODE){
    const unsigned short* hp = Hn + (size_t)n*128 + part*32;
#pragma unroll
    for (int k=0;k<32;++k){
      float x = ftanh(bf2f(hp[k]));
      vals[k] = x; s += x; ss += x*x;
    }
  } else {
#pragma unroll
    for (int k=0;k<32;++k) vals[k] = 0.f;
  }
  s  += __shfl_xor(s,1);  s  += __shfl_xor(s,2);
  ss += __shfl_xor(ss,1); ss += __shfl_xor(ss,2);
  float mu = s * (1.f/128.f);
  float var = ss * (1.f/128.f) - mu*mu;
  float inv = rsqrtf(fmaxf(var, 0.f) + 1e-5f);
#pragma unroll
  for (int k=0;k<32;++k){
    int d = part*32 + k;
    xn[row*128 + d] = f2bf((vals[k]-mu)*inv*gam[d] + bet[d]);
  }
  __syncthreads();
  int w = tid >> 6, l = tid & 63;
  const f32x4 vzero = {0.f,0.f,0.f,0.f};
  f32x4 acc[5];
#pragma unroll
  for (int tj=0;tj<5;++tj) acc[tj] = vzero;
#pragma unroll
  for (int kk=0;kk<4;++kk){
    bf16x8 a = *(const bf16x8*)(xn + (w*16 + (l&15))*128 + kk*32 + (l>>4)*8);
#pragma unroll
    for (int tj=0;tj<5;++tj){
      bf16x8 b = *(const bf16x8*)(w1s + (tj*16 + (l&15))*128 + kk*32 + (l>>4)*8);
      acc[tj] = __builtin_amdgcn_mfma_f32_16x16x32_bf16(a, b, acc[tj], 0,0,0);
    }
  }
#pragma unroll
  for (int r=0;r<4;++r){
    int rn = n0 + w*16 + (l>>4)*4 + r;
    float p0 = 0.f, p1 = 0.f;
#pragma unroll
    for (int tj=0;tj<5;++tj){
      int col = tj*16 + (l&15);
      float hv = fmaxf(acc[tj][r] + b1s[col], 0.f);
      p0 += hv * w2s[col*2];
      p1 += hv * w2s[col*2+1];
    }
    p0 += __shfl_xor(p0,1); p0 += __shfl_xor(p0,2); p0 += __shfl_xor(p0,4); p0 += __shfl_xor(p0,8);
    p1 += __shfl_xor(p1,1); p1 += __shfl_xor(p1,2); p1 += __shfl_xor(p1,4); p1 += __shfl_xor(p1,8);
    if ((l & 15) == 0 && rn < N_NODE){
      float* op = out + (size_t)rn*24 + t;   // out[n][c][s], C=2, S=12
      op[0]  = sigf(p0 + b2s[0]);
      op[12] = sigf(p1 + b2s[1]);
    }
  }
}

extern "C" void kernel_launch(void* const* d_in, const int* in_sizes, int n_in,
                              void* d_out, int out_size, void* d_ws, size_t ws_size,
                              hipStream_t stream)
{
  const float* H   = (const float*)d_in[0];
  const int*   ei  = (const int*)d_in[1];
  const float* Wx  = (const float*)d_in[2];
  const float* bx  = (const float*)d_in[3];
  const float* Wh  = (const float*)d_in[4];
  const float* bh  = (const float*)d_in[5];
  const float* bg  = (const float*)d_in[6];
  const float* wc  = (const float*)d_in[7];
  const float* gam = (const float*)d_in[8];
  const float* bet = (const float*)d_in[9];
  const float* W1  = (const float*)d_in[10];
  const float* b1  = (const float*)d_in[11];
  const float* W2  = (const float*)d_in[12];
  const float* b2  = (const float*)d_in[13];
  float* out = (float*)d_out;
  (void)in_sizes; (void)n_in; (void)out_size; (void)ws_size;

  char* p = (char*)d_ws;
  auto alloc = [&](size_t bytes)->char*{ char* r = p; p += (bytes + 255) & ~(size_t)255; return r; };
  // ---- zeroed region (one memset) ----
  char* zbase = p;
  float*          c_st  = (float*)alloc((size_t)N_PAD*128*4);
  unsigned short* Hbuf0 = (unsigned short*)alloc((size_t)N_PAD*128*2);
  int* dsrc   = (int*)alloc((size_t)N_P2*4);
  int* ddst   = (int*)alloc((size_t)N_P2*4);
  int* cursor = (int*)alloc((size_t)N_P2*4);
  size_t zbytes = (size_t)(p - zbase);
  // ---- rest ----
  unsigned short* Hbuf1 = (unsigned short*)alloc((size_t)N_PAD*128*2);
  unsigned short* Ubuf  = (unsigned short*)alloc((size_t)N_PAD*256*2);
  unsigned short* Xbf   = (unsigned short*)alloc((size_t)S_DIM*N_PAD*64*2);
  unsigned short* Axt   = (unsigned short*)alloc((size_t)S_DIM*N_PAD*128*2);
  unsigned short* Bct   = (unsigned short*)alloc((size_t)N_COL*K_TOT*2);
  float*          btot  = (float*)alloc(N_COL*4);
  unsigned short* W1t   = (unsigned short*)alloc(HID_P*128*2);
  float*          b1p   = (float*)alloc(HID_P*4);
  float*          W2p   = (float*)alloc(HID_P*2*4);
  float*          dinv  = (float*)alloc((size_t)N_P2*4);
  int*            offs  = (int*)alloc((size_t)(N_P2+256)*4);
  int*            outp  = (int*)alloc((size_t)N_P2*4);
  int*            partb = (int*)alloc(256*4);
  int2*           cedge = (int2*)alloc((size_t)N_E*8);

  hipMemsetAsync(zbase, 0, zbytes, stream);
  k_prep<<<(N_COL*K_TOT + 255)/256, 256, 0, stream>>>(Wx, Wh, bx, bh, bg, W1, b1, W2,
                                                      Bct, btot, W1t, b1p, W2p);
  k_xcvt<<<(int)((size_t)S_DIM*N_PAD*64/2048), 256, 0, stream>>>(H, Xbf);
  k_deg<<<(N_E + 255)/256, 256, 0, stream>>>(ei, dsrc, ddst);
  k_dinv<<<N_P2/256, 256, 0, stream>>>(dsrc, dinv);
  k_scan1<<<N_P2/256, 256, 0, stream>>>(ddst, outp, partb);
  k_scan2<<<1, 256, 0, stream>>>(partb, N_P2/256);
  k_scan3<<<N_P2/256, 256, 0, stream>>>(outp, partb, offs);
  k_csr<<<(N_E + 255)/256, 256, 0, stream>>>(ei, dinv, offs, cursor, cedge);
  k_xspmm1<<<dim3(N_NODE/4, S_DIM/2), 256, 0, stream>>>(Xbf, Axt, offs, cedge);
  k_xspmm2<<<dim3(N_NODE/4, S_DIM/2), 256, 0, stream>>>(Axt, offs, cedge);

  for (int t = 0; t < S_DIM; ++t){
    unsigned short* Hc = (t & 1) ? Hbuf1 : Hbuf0;
    unsigned short* Hn = (t & 1) ? Hbuf0 : Hbuf1;
    k_spmm1<<<N_NODE/4, 256, 0, stream>>>(Hc, Ubuf, offs, cedge);
    k_spmm2<<<N_NODE/4, 256, 0, stream>>>(Ubuf, offs, cedge);
    k_gemm<<<dim3(4, N_PAD/128), 256, 0, stream>>>(Hc, Ubuf,
        Xbf + (size_t)t*N_PAD*64, Axt + (size_t)t*N_PAD*128,
        Bct, btot, wc, c_st, Hn);
    k_lnmlp<<<N_PAD/64, 256, 0, stream>>>(Hn, W1t, b1p, W2p, b2, gam, bet, out, t);
  }
}

// Round 3
// 2074.531 us; speedup vs baseline: 1.5519x; 1.5159x over previous
//
#include <hip/hip_runtime.h>
#include <cstdint>
#include <cstddef>

#define S_DIM 12
#define N_NODE 50000
#define N_PAD 50048
#define N_P2 50176
#define D_IN 64
#define D_H 128
#define N_E 600000
#define K_TOT 576   // 128 h + 256 (u1h|u2h) + 64 x + 128 (u1x|u2x)
#define N_COL 512   // 4 gates x 128, interleaved cc = (d&15) + 16*g + 64*(d>>4)
#define HID_P 80
#define N_HID 65
#define AXC 192     // Axt cols: [x | u1x | u2x]

typedef short bf16x8 __attribute__((ext_vector_type(8)));
typedef float f32x4 __attribute__((ext_vector_type(4)));

__device__ __forceinline__ float bf2f(unsigned short u){
  union { unsigned int i; float f; } v; v.i = ((unsigned int)u) << 16; return v.f;
}
__device__ __forceinline__ unsigned short f2bf(float f){
  union { float f; unsigned int i; } v; v.f = f;
  unsigned int x = v.i;
  return (unsigned short)((x + 0x7fffu + ((x >> 16) & 1u)) >> 16);
}
__device__ __forceinline__ float sigf(float x){ return 1.f/(1.f + __expf(-x)); }
__device__ __forceinline__ float ftanh(float x){
  x = fminf(fmaxf(x, -12.f), 12.f);
  float e = __expf(2.f*x);
  return (e - 1.f)/(e + 1.f);
}

__device__ __forceinline__ void gload16(const void* g, void* lds){
  __builtin_amdgcn_global_load_lds((const __attribute__((address_space(1))) unsigned int*)g,
                                   (__attribute__((address_space(3))) unsigned int*)lds, 16, 0, 0);
}

// accumulate 12 bf16 (3 x uint2) * w into a[12]
__device__ __forceinline__ void acc12(float* a, uint2 p0, uint2 p1, uint2 p2, float w){
  unsigned int u[6] = {p0.x, p0.y, p1.x, p1.y, p2.x, p2.y};
#pragma unroll
  for (int i=0;i<6;++i){
    a[2*i]   += w * bf2f((unsigned short)(u[i] & 0xffffu));
    a[2*i+1] += w * bf2f((unsigned short)(u[i] >> 16));
  }
}

// ---------------- prep: pack weights (gate-interleaved cols + Chebyshev fold) ----
__global__ void k_prep(const float* __restrict__ Wx, const float* __restrict__ Wh,
                       const float* __restrict__ bx, const float* __restrict__ bh,
                       const float* __restrict__ bg, const float* __restrict__ W1,
                       const float* __restrict__ b1, const float* __restrict__ W2,
                       unsigned short* __restrict__ Bct, float* __restrict__ btot,
                       unsigned short* __restrict__ W1t, float* __restrict__ b1p,
                       float* __restrict__ W2p)
{
  int idx = blockIdx.x*256 + threadIdx.x;
  if (idx < N_COL*K_TOT){
    int cc = idx / K_TOT, k = idx - cc*K_TOT;
    int g = (cc>>4)&3, d = (cc&15) + ((cc>>6)<<4);
    float v;
    if (k < 384){
      int kt = k >> 7, j = k & 127;
      const float* Wg = Wh + (size_t)g*3*128*128;
      if (kt == 0)      v = Wg[(size_t)j*128 + d] - Wg[(size_t)(256+j)*128 + d];
      else if (kt == 1) v = Wg[(size_t)(128+j)*128 + d];
      else              v = 2.f*Wg[(size_t)(256+j)*128 + d];
    } else {
      int kk = k - 384; int kt = kk >> 6, j = kk & 63;
      const float* Wg = Wx + (size_t)g*3*64*128;
      if (kt == 0)      v = Wg[(size_t)j*128 + d] - Wg[(size_t)(128+j)*128 + d];
      else if (kt == 1) v = Wg[(size_t)(64+j)*128 + d];
      else              v = 2.f*Wg[(size_t)(128+j)*128 + d];
    }
    Bct[(size_t)cc*K_TOT + k] = f2bf(v);
  }
  if (idx < N_COL) btot[idx] = bx[idx] + bh[idx] + bg[idx];
  if (idx < HID_P*D_H){ int c = idx >> 7, k = idx & 127;
    W1t[idx] = (c < N_HID) ? f2bf(W1[k*N_HID + c]) : (unsigned short)0; }
  if (idx < HID_P) b1p[idx] = (idx < N_HID) ? b1[idx] : 0.f;
  if (idx < HID_P*2){ int c = idx >> 1, j = idx & 1; W2p[idx] = (c < N_HID) ? W2[c*2 + j] : 0.f; }
}

// ---------------- x conversion: H -> Xtr [n][d][12] + Axt x-planes ----------------
__global__ void k_xprep(const float* __restrict__ H, unsigned short* __restrict__ Xtr,
                        unsigned short* __restrict__ Axt){
  int idx = blockIdx.x*256 + threadIdx.x;    // (n,d)
  if (idx >= N_PAD*64) return;
  int n = idx >> 6, d = idx & 63;
  union { unsigned short u[12]; uint2 q[3]; } pk;
  if (n < N_NODE){
#pragma unroll
    for (int t=0;t<12;++t) pk.u[t] = f2bf(H[((size_t)t*N_NODE + n)*64 + d]);
  } else {
#pragma unroll
    for (int t=0;t<12;++t) pk.u[t] = 0;
  }
  uint2* xp = (uint2*)(Xtr + (size_t)idx*12);
  xp[0]=pk.q[0]; xp[1]=pk.q[1]; xp[2]=pk.q[2];
#pragma unroll
  for (int t=0;t<12;++t) Axt[((size_t)t*N_PAD + n)*AXC + d] = pk.u[t];
  if (n >= N_NODE){
#pragma unroll
    for (int t=0;t<12;++t){
      Axt[((size_t)t*N_PAD + n)*AXC + 64 + d]  = 0;
      Axt[((size_t)t*N_PAD + n)*AXC + 128 + d] = 0;
    }
  }
}

// ---------------- graph preprocessing ----------------
__global__ void k_deg(const int* __restrict__ ei, int* __restrict__ dsrc, int* __restrict__ ddst){
  int e = blockIdx.x*256 + threadIdx.x;
  if (e < N_E){
    atomicAdd(&dsrc[ei[e]], 1);
    atomicAdd(&ddst[ei[N_E + e]], 1);
  }
}
__global__ void k_dinv(const int* __restrict__ dsrc, float* __restrict__ dinv){
  int n = blockIdx.x*256 + threadIdx.x;
  if (n < N_P2) dinv[n] = (dsrc[n] > 0) ? rsqrtf((float)dsrc[n]) : 0.f;
}
__global__ void k_scan1(const int* __restrict__ in, int* __restrict__ outp, int* __restrict__ part){
  __shared__ int sm[256];
  int tid = threadIdx.x;
  int i = blockIdx.x*256 + tid;
  int v = in[i];
  int x = v;
  sm[tid] = x; __syncthreads();
  for (int off=1; off<256; off<<=1){
    int y = (tid >= off) ? sm[tid-off] : 0;
    __syncthreads();
    x += y; sm[tid] = x; __syncthreads();
  }
  outp[i] = x - v;
  if (tid == 255) part[blockIdx.x] = x;
}
__global__ void k_scan2(int* __restrict__ part, int nblk){
  __shared__ int sm[256];
  int tid = threadIdx.x;
  int v = (tid < nblk) ? part[tid] : 0;
  int x = v; sm[tid] = x; __syncthreads();
  for (int off=1; off<256; off<<=1){
    int y = (tid >= off) ? sm[tid-off] : 0;
    __syncthreads();
    x += y; sm[tid] = x; __syncthreads();
  }
  if (tid < nblk) part[tid] = x - v;
}
__global__ void k_scan3(const int* __restrict__ outp, const int* __restrict__ part, int* __restrict__ offs){
  int i = blockIdx.x*256 + threadIdx.x;
  offs[i] = outp[i] + part[blockIdx.x];
}
__global__ void k_csr(const int* __restrict__ ei, const float* __restrict__ dinv,
                      const int* __restrict__ offs, int* __restrict__ cursor,
                      int2* __restrict__ cedge){
  int e = blockIdx.x*256 + threadIdx.x;
  if (e < N_E){
    int s = ei[e], d = ei[N_E + e];
    int pos = atomicAdd(&cursor[d], 1);
    float w = -dinv[s]*dinv[d];
    cedge[offs[d] + pos] = make_int2(s, __float_as_int(w));
  }
}

// ---------------- x-side spmm, all 12 t at once via [n][d][t] gathers -----------
// u1x: gather Xtr rows; write Axt[t][n][64+l] and U1tr[n][l][t]
__global__ void k_xspmm1(const unsigned short* __restrict__ Xtr, unsigned short* __restrict__ Axt,
                         unsigned short* __restrict__ U1tr,
                         const int* __restrict__ offs, const int2* __restrict__ cedge){
  int n = blockIdx.x*4 + (threadIdx.x >> 6);
  int l = threadIdx.x & 63;
  if (n >= N_NODE) return;
  int beg = offs[n], end = offs[n+1];
  float a[12];
#pragma unroll
  for (int t=0;t<12;++t) a[t] = 0.f;
  int q = beg;
  for (; q+2 <= end; q += 2){
    int2 e0 = cedge[q], e1 = cedge[q+1];
    const uint2* r0 = (const uint2*)(Xtr + ((size_t)e0.x*64 + l)*12);
    const uint2* r1 = (const uint2*)(Xtr + ((size_t)e1.x*64 + l)*12);
    uint2 p00=r0[0], p01=r0[1], p02=r0[2];
    uint2 p10=r1[0], p11=r1[1], p12=r1[2];
    acc12(a, p00, p01, p02, __int_as_float(e0.y));
    acc12(a, p10, p11, p12, __int_as_float(e1.y));
  }
  if (q < end){
    int2 e0 = cedge[q];
    const uint2* r0 = (const uint2*)(Xtr + ((size_t)e0.x*64 + l)*12);
    acc12(a, r0[0], r0[1], r0[2], __int_as_float(e0.y));
  }
  union { unsigned short u[12]; uint2 qq[3]; } pk;
#pragma unroll
  for (int t=0;t<12;++t){
    unsigned short b = f2bf(a[t]);
    pk.u[t] = b;
    Axt[((size_t)t*N_PAD + n)*AXC + 64 + l] = b;
  }
  uint2* op = (uint2*)(U1tr + ((size_t)n*64 + l)*12);
  op[0]=pk.qq[0]; op[1]=pk.qq[1]; op[2]=pk.qq[2];
}
// u2x = L@u1x (pure; Chebyshev constants folded into B): gather U1tr
__global__ void k_xspmm2(const unsigned short* __restrict__ U1tr, unsigned short* __restrict__ Axt,
                         const int* __restrict__ offs, const int2* __restrict__ cedge){
  int n = blockIdx.x*4 + (threadIdx.x >> 6);
  int l = threadIdx.x & 63;
  if (n >= N_NODE) return;
  int beg = offs[n], end = offs[n+1];
  float a[12];
#pragma unroll
  for (int t=0;t<12;++t) a[t] = 0.f;
  int q = beg;
  for (; q+2 <= end; q += 2){
    int2 e0 = cedge[q], e1 = cedge[q+1];
    const uint2* r0 = (const uint2*)(U1tr + ((size_t)e0.x*64 + l)*12);
    const uint2* r1 = (const uint2*)(U1tr + ((size_t)e1.x*64 + l)*12);
    uint2 p00=r0[0], p01=r0[1], p02=r0[2];
    uint2 p10=r1[0], p11=r1[1], p12=r1[2];
    acc12(a, p00, p01, p02, __int_as_float(e0.y));
    acc12(a, p10, p11, p12, __int_as_float(e1.y));
  }
  if (q < end){
    int2 e0 = cedge[q];
    const uint2* r0 = (const uint2*)(U1tr + ((size_t)e0.x*64 + l)*12);
    acc12(a, r0[0], r0[1], r0[2], __int_as_float(e0.y));
  }
#pragma unroll
  for (int t=0;t<12;++t)
    Axt[((size_t)t*N_PAD + n)*AXC + 128 + l] = f2bf(a[t]);
}

// ---------------- per-step h-side spmm (4x edge unroll for ILP) ----------------
__global__ void k_spmm1(const unsigned short* __restrict__ Hc, unsigned short* __restrict__ U,
                        const int* __restrict__ offs, const int2* __restrict__ cedge){
  int n = blockIdx.x*4 + (threadIdx.x >> 6);
  int l = threadIdx.x & 63;
  if (n >= N_NODE) return;
  int beg = offs[n], end = offs[n+1];
  float a0 = 0.f, a1 = 0.f;
  int q = beg;
  for (; q+4 <= end; q += 4){
    int2 e0=cedge[q], e1=cedge[q+1], e2=cedge[q+2], e3=cedge[q+3];
    unsigned int h0 = *(const unsigned int*)(Hc + (size_t)e0.x*128 + 2*l);
    unsigned int h1 = *(const unsigned int*)(Hc + (size_t)e1.x*128 + 2*l);
    unsigned int h2 = *(const unsigned int*)(Hc + (size_t)e2.x*128 + 2*l);
    unsigned int h3 = *(const unsigned int*)(Hc + (size_t)e3.x*128 + 2*l);
    float w0=__int_as_float(e0.y), w1=__int_as_float(e1.y),
          w2=__int_as_float(e2.y), w3=__int_as_float(e3.y);
    a0 += w0*bf2f((unsigned short)(h0&0xffffu)); a1 += w0*bf2f((unsigned short)(h0>>16));
    a0 += w1*bf2f((unsigned short)(h1&0xffffu)); a1 += w1*bf2f((unsigned short)(h1>>16));
    a0 += w2*bf2f((unsigned short)(h2&0xffffu)); a1 += w2*bf2f((unsigned short)(h2>>16));
    a0 += w3*bf2f((unsigned short)(h3&0xffffu)); a1 += w3*bf2f((unsigned short)(h3>>16));
  }
  for (; q < end; ++q){
    int2 e = cedge[q]; float w = __int_as_float(e.y);
    unsigned int hv = *(const unsigned int*)(Hc + (size_t)e.x*128 + 2*l);
    a0 += w*bf2f((unsigned short)(hv&0xffffu)); a1 += w*bf2f((unsigned short)(hv>>16));
  }
  *(unsigned int*)(U + (size_t)n*256 + 2*l) =
      ((unsigned int)f2bf(a1) << 16) | (unsigned int)f2bf(a0);
}
__global__ void k_spmm2(unsigned short* __restrict__ U,
                        const int* __restrict__ offs, const int2* __restrict__ cedge){
  int n = blockIdx.x*4 + (threadIdx.x >> 6);
  int l = threadIdx.x & 63;
  if (n >= N_NODE) return;
  int beg = offs[n], end = offs[n+1];
  float a0 = 0.f, a1 = 0.f;
  int q = beg;
  for (; q+4 <= end; q += 4){
    int2 e0=cedge[q], e1=cedge[q+1], e2=cedge[q+2], e3=cedge[q+3];
    unsigned int h0 = *(const unsigned int*)(U + (size_t)e0.x*256 + 2*l);
    unsigned int h1 = *(const unsigned int*)(U + (size_t)e1.x*256 + 2*l);
    unsigned int h2 = *(const unsigned int*)(U + (size_t)e2.x*256 + 2*l);
    unsigned int h3 = *(const unsigned int*)(U + (size_t)e3.x*256 + 2*l);
    float w0=__int_as_float(e0.y), w1=__int_as_float(e1.y),
          w2=__int_as_float(e2.y), w3=__int_as_float(e3.y);
    a0 += w0*bf2f((unsigned short)(h0&0xffffu)); a1 += w0*bf2f((unsigned short)(h0>>16));
    a0 += w1*bf2f((unsigned short)(h1&0xffffu)); a1 += w1*bf2f((unsigned short)(h1>>16));
    a0 += w2*bf2f((unsigned short)(h2&0xffffu)); a1 += w2*bf2f((unsigned short)(h2>>16));
    a0 += w3*bf2f((unsigned short)(h3&0xffffu)); a1 += w3*bf2f((unsigned short)(h3>>16));
  }
  for (; q < end; ++q){
    int2 e = cedge[q]; float w = __int_as_float(e.y);
    unsigned int hv = *(const unsigned int*)(U + (size_t)e.x*256 + 2*l);
    a0 += w*bf2f((unsigned short)(hv&0xffffu)); a1 += w*bf2f((unsigned short)(hv>>16));
  }
  *(unsigned int*)(U + (size_t)n*256 + 128 + 2*l) =
      ((unsigned int)f2bf(a1) << 16) | (unsigned int)f2bf(a0);
}

// ---------------- fused GEMM + LSTM gates ----------------
__global__ __launch_bounds__(256,2) void k_gemm(
    const unsigned short* __restrict__ Hc, const unsigned short* __restrict__ U,
    const unsigned short* __restrict__ Axt,
    const unsigned short* __restrict__ Bct, const float* __restrict__ btot,
    const float* __restrict__ wc, float* __restrict__ c, unsigned short* __restrict__ Hn)
{
  __shared__ __align__(16) unsigned short As[128*64];
  __shared__ __align__(16) unsigned short Bs[128*64];
  int tid = threadIdx.x;
  int w = tid >> 6, l = tid & 63;
  const int NWG = 1564, q8 = NWG >> 3, r8 = NWG & 7;
  int L = blockIdx.y*4 + blockIdx.x;
  int xcd = L & 7, li = L >> 3;
  int W = (xcd < r8 ? xcd*(q8+1) : r8*(q8+1) + (xcd-r8)*q8) + li;
  int bx = W & 3, by = W >> 2;
  int n0 = bx * 128;
  int m0 = by * 128;
  const f32x4 vzero = {0.f,0.f,0.f,0.f};
  f32x4 acc[4][4];
#pragma unroll
  for (int i=0;i<4;++i)
#pragma unroll
    for (int j=0;j<4;++j) acc[i][j] = vzero;
  int wr = w >> 1, wn = w & 1;
  for (int it=0; it<9; ++it){
    const unsigned short* Ab; int astr, acol;
    if (it < 2)      { Ab = Hc;  astr = 128; acol = it*64; }
    else if (it < 6) { Ab = U;   astr = 256; acol = (it-2)*64; }
    else             { Ab = Axt; astr = AXC; acol = (it-6)*64; }
    if (it) __syncthreads();
#pragma unroll
    for (int i=0;i<4;++i){
      int rr = w*32 + i*8;
      int row = rr + (l>>3);
      gload16(Ab  + (size_t)(m0+row)*astr + acol + (l&7)*8, (void*)(As + rr*64));
      gload16(Bct + (size_t)(n0+row)*K_TOT + it*64 + (l&7)*8, (void*)(Bs + rr*64));
    }
    __syncthreads();
#pragma unroll
    for (int kk=0; kk<2; ++kk){
      bf16x8 af[4], bfv[4];
#pragma unroll
      for (int i=0;i<4;++i) af[i]  = *(const bf16x8*)(As + (wr*64 + i*16 + (l&15))*64 + kk*32 + (l>>4)*8);
#pragma unroll
      for (int j=0;j<4;++j) bfv[j] = *(const bf16x8*)(Bs + (wn*64 + j*16 + (l&15))*64 + kk*32 + (l>>4)*8);
#pragma unroll
      for (int i=0;i<4;++i)
#pragma unroll
        for (int j=0;j<4;++j)
          acc[i][j] = __builtin_amdgcn_mfma_f32_16x16x32_bf16(af[i], bfv[j], acc[i][j], 0,0,0);
    }
  }
  int dd = (((bx<<1) + wn) << 4) | (l & 15);
  float b_i = btot[dd], b_f = btot[128+dd], b_t = btot[256+dd], b_o = btot[384+dd];
  float wci = wc[dd], wcf = wc[128+dd], wco = wc[256+dd];
#pragma unroll
  for (int i=0;i<4;++i){
    int row0 = m0 + wr*64 + i*16 + (l>>4)*4;
#pragma unroll
    for (int r=0;r<4;++r){
      int row = row0 + r;
      float co = c[(size_t)row*128 + dd];
      float gi = sigf(acc[i][0][r] + b_i + wci*co);
      float gf = sigf(acc[i][1][r] + b_f + wcf*co);
      float tt = ftanh(acc[i][2][r] + b_t);
      float cn = gf*co + gi*tt;
      float go = sigf(acc[i][3][r] + b_o + wco*cn);
      float h = go * ftanh(cn);
      c[(size_t)row*128 + dd] = cn;
      Hn[(size_t)row*128 + dd] = f2bf(h);
    }
  }
}

// ---------------- tanh + LN + MLP + sigmoid + transpose (per step) ----------------
__global__ __launch_bounds__(256,2) void k_lnmlp(const unsigned short* __restrict__ Hn,
                        const unsigned short* __restrict__ W1t, const float* __restrict__ b1p,
                        const float* __restrict__ W2p, const float* __restrict__ b2,
                        const float* __restrict__ gam, const float* __restrict__ bet,
                        float* __restrict__ out, int t)
{
  __shared__ __align__(16) unsigned short xn[64*128];
  __shared__ __align__(16) unsigned short w1s[HID_P*128];
  __shared__ float w2s[HID_P*2];
  __shared__ float b1s[HID_P];
  __shared__ float b2s[2];
  int tid = threadIdx.x;
  for (int i = tid; i < HID_P*128/8; i += 256) ((int4*)w1s)[i] = ((const int4*)W1t)[i];
  if (tid < HID_P*2) w2s[tid] = W2p[tid];
  if (tid < HID_P)   b1s[tid] = b1p[tid];
  if (tid < 2)       b2s[tid] = b2[tid];
  int n0 = blockIdx.x*64;
  int row = tid >> 2, part = tid & 3;
  int n = n0 + row;
  float vals[32];
  float s = 0.f, ss = 0.f;
  if (n < N_NODE){
    const unsigned short* hp = Hn + (size_t)n*128 + part*32;
#pragma unroll
    for (int k=0;k<32;++k){
      float x = ftanh(bf2f(hp[k]));
      vals[k] = x; s += x; ss += x*x;
    }
  } else {
#pragma unroll
    for (int k=0;k<32;++k) vals[k] = 0.f;
  }
  s  += __shfl_xor(s,1);  s  += __shfl_xor(s,2);
  ss += __shfl_xor(ss,1); ss += __shfl_xor(ss,2);
  float mu = s * (1.f/128.f);
  float var = ss * (1.f/128.f) - mu*mu;
  float inv = rsqrtf(fmaxf(var, 0.f) + 1e-5f);
#pragma unroll
  for (int k=0;k<32;++k){
    int d = part*32 + k;
    xn[row*128 + d] = f2bf((vals[k]-mu)*inv*gam[d] + bet[d]);
  }
  __syncthreads();
  int w = tid >> 6, l = tid & 63;
  const f32x4 vzero = {0.f,0.f,0.f,0.f};
  f32x4 acc[5];
#pragma unroll
  for (int tj=0;tj<5;++tj) acc[tj] = vzero;
#pragma unroll
  for (int kk=0;kk<4;++kk){
    bf16x8 a = *(const bf16x8*)(xn + (w*16 + (l&15))*128 + kk*32 + (l>>4)*8);
#pragma unroll
    for (int tj=0;tj<5;++tj){
      bf16x8 b = *(const bf16x8*)(w1s + (tj*16 + (l&15))*128 + kk*32 + (l>>4)*8);
      acc[tj] = __builtin_amdgcn_mfma_f32_16x16x32_bf16(a, b, acc[tj], 0,0,0);
    }
  }
#pragma unroll
  for (int r=0;r<4;++r){
    int rn = n0 + w*16 + (l>>4)*4 + r;
    float p0 = 0.f, p1 = 0.f;
#pragma unroll
    for (int tj=0;tj<5;++tj){
      int col = tj*16 + (l&15);
      float hv = fmaxf(acc[tj][r] + b1s[col], 0.f);
      p0 += hv * w2s[col*2];
      p1 += hv * w2s[col*2+1];
    }
    p0 += __shfl_xor(p0,1); p0 += __shfl_xor(p0,2); p0 += __shfl_xor(p0,4); p0 += __shfl_xor(p0,8);
    p1 += __shfl_xor(p1,1); p1 += __shfl_xor(p1,2); p1 += __shfl_xor(p1,4); p1 += __shfl_xor(p1,8);
    if ((l & 15) == 0 && rn < N_NODE){
      float* op = out + (size_t)rn*24 + t;   // out[n][c][s], C=2, S=12
      op[0]  = sigf(p0 + b2s[0]);
      op[12] = sigf(p1 + b2s[1]);
    }
  }
}

extern "C" void kernel_launch(void* const* d_in, const int* in_sizes, int n_in,
                              void* d_out, int out_size, void* d_ws, size_t ws_size,
                              hipStream_t stream)
{
  const float* H   = (const float*)d_in[0];
  const int*   ei  = (const int*)d_in[1];
  const float* Wx  = (const float*)d_in[2];
  const float* bx  = (const float*)d_in[3];
  const float* Wh  = (const float*)d_in[4];
  const float* bh  = (const float*)d_in[5];
  const float* bg  = (const float*)d_in[6];
  const float* wc  = (const float*)d_in[7];
  const float* gam = (const float*)d_in[8];
  const float* bet = (const float*)d_in[9];
  const float* W1  = (const float*)d_in[10];
  const float* b1  = (const float*)d_in[11];
  const float* W2  = (const float*)d_in[12];
  const float* b2  = (const float*)d_in[13];
  float* out = (float*)d_out;
  (void)in_sizes; (void)n_in; (void)out_size; (void)ws_size;

  char* p = (char*)d_ws;
  auto alloc = [&](size_t bytes)->char*{ char* r = p; p += (bytes + 255) & ~(size_t)255; return r; };
  // ---- zeroed region (one memset) ----
  char* zbase = p;
  float*          c_st  = (float*)alloc((size_t)N_PAD*128*4);
  unsigned short* Hbuf0 = (unsigned short*)alloc((size_t)N_PAD*128*2);
  int* dsrc   = (int*)alloc((size_t)N_P2*4);
  int* ddst   = (int*)alloc((size_t)N_P2*4);
  int* cursor = (int*)alloc((size_t)N_P2*4);
  size_t zbytes = (size_t)(p - zbase);
  // ---- rest ----
  unsigned short* Hbuf1 = (unsigned short*)alloc((size_t)N_PAD*128*2);
  unsigned short* Ubuf  = (unsigned short*)alloc((size_t)N_PAD*256*2);
  unsigned short* Xtr   = (unsigned short*)alloc((size_t)N_PAD*64*12*2);
  unsigned short* U1tr  = (unsigned short*)alloc((size_t)N_PAD*64*12*2);
  unsigned short* Axt   = (unsigned short*)alloc((size_t)S_DIM*N_PAD*AXC*2);
  unsigned short* Bct   = (unsigned short*)alloc((size_t)N_COL*K_TOT*2);
  float*          btot  = (float*)alloc(N_COL*4);
  unsigned short* W1t   = (unsigned short*)alloc(HID_P*128*2);
  float*          b1p   = (float*)alloc(HID_P*4);
  float*          W2p   = (float*)alloc(HID_P*2*4);
  float*          dinv  = (float*)alloc((size_t)N_P2*4);
  int*            offs  = (int*)alloc((size_t)(N_P2+256)*4);
  int*            outp  = (int*)alloc((size_t)N_P2*4);
  int*            partb = (int*)alloc(256*4);
  int2*           cedge = (int2*)alloc((size_t)N_E*8);

  hipMemsetAsync(zbase, 0, zbytes, stream);
  k_prep<<<(N_COL*K_TOT + 255)/256, 256, 0, stream>>>(Wx, Wh, bx, bh, bg, W1, b1, W2,
                                                      Bct, btot, W1t, b1p, W2p);
  k_xprep<<<(N_PAD*64 + 255)/256, 256, 0, stream>>>(H, Xtr, Axt);
  k_deg<<<(N_E + 255)/256, 256, 0, stream>>>(ei, dsrc, ddst);
  k_dinv<<<N_P2/256, 256, 0, stream>>>(dsrc, dinv);
  k_scan1<<<N_P2/256, 256, 0, stream>>>(ddst, outp, partb);
  k_scan2<<<1, 256, 0, stream>>>(partb, N_P2/256);
  k_scan3<<<N_P2/256, 256, 0, stream>>>(outp, partb, offs);
  k_csr<<<(N_E + 255)/256, 256, 0, stream>>>(ei, dinv, offs, cursor, cedge);
  k_xspmm1<<<N_NODE/4, 256, 0, stream>>>(Xtr, Axt, U1tr, offs, cedge);
  k_xspmm2<<<N_NODE/4, 256, 0, stream>>>(U1tr, Axt, offs, cedge);

  for (int t = 0; t < S_DIM; ++t){
    unsigned short* Hc = (t & 1) ? Hbuf1 : Hbuf0;
    unsigned short* Hn = (t & 1) ? Hbuf0 : Hbuf1;
    k_spmm1<<<N_NODE/4, 256, 0, stream>>>(Hc, Ubuf, offs, cedge);
    k_spmm2<<<N_NODE/4, 256, 0, stream>>>(Ubuf, offs, cedge);
    k_gemm<<<dim3(4, N_PAD/128), 256, 0, stream>>>(Hc, Ubuf,
        Axt + (size_t)t*N_PAD*AXC, Bct, btot, wc, c_st, Hn);
    k_lnmlp<<<N_PAD/64, 256, 0, stream>>>(Hn, W1t, b1p, W2p, b2, gam, bet, out, t);
  }
}

// Round 4
// 1972.939 us; speedup vs baseline: 1.6318x; 1.0515x over previous
//
#include <hip/hip_runtime.h>
#include <cstdint>
#include <cstddef>

#define S_DIM 12
#define N_NODE 50000
#define N_PAD 50048
#define N_P2 50176
#define D_IN 64
#define D_H 128
#define N_E 600000
#define K_TOT 576   // 128 h + 256 (u1h|u2h) + 64 x + 128 (u1x|u2x)
#define N_COL 512   // 4 gates x 128, interleaved cc = (d&15) + 16*g + 64*(d>>4)
#define HID_P 80
#define N_HID 65
#define AXC 192     // Axt cols: [x | u1x | u2x]

typedef short bf16x8 __attribute__((ext_vector_type(8)));
typedef float f32x4 __attribute__((ext_vector_type(4)));

__device__ __forceinline__ float bf2f(unsigned short u){
  union { unsigned int i; float f; } v; v.i = ((unsigned int)u) << 16; return v.f;
}
__device__ __forceinline__ unsigned short f2bf(float f){
  union { float f; unsigned int i; } v; v.f = f;
  unsigned int x = v.i;
  return (unsigned short)((x + 0x7fffu + ((x >> 16) & 1u)) >> 16);
}
__device__ __forceinline__ float sigf(float x){ return 1.f/(1.f + __expf(-x)); }
__device__ __forceinline__ float ftanh(float x){
  x = fminf(fmaxf(x, -12.f), 12.f);
  float e = __expf(2.f*x);
  return (e - 1.f)/(e + 1.f);
}

__device__ __forceinline__ void gload16(const void* g, void* lds){
  __builtin_amdgcn_global_load_lds((const __attribute__((address_space(1))) unsigned int*)g,
                                   (__attribute__((address_space(3))) unsigned int*)lds, 16, 0, 0);
}

// accumulate 12 bf16 (3 x uint2) * w into a[12]
__device__ __forceinline__ void acc12(float* a, uint2 p0, uint2 p1, uint2 p2, float w){
  unsigned int u[6] = {p0.x, p0.y, p1.x, p1.y, p2.x, p2.y};
#pragma unroll
  for (int i=0;i<6;++i){
    a[2*i]   += w * bf2f((unsigned short)(u[i] & 0xffffu));
    a[2*i+1] += w * bf2f((unsigned short)(u[i] >> 16));
  }
}
// accumulate 8 bf16 (uint4) * w into a[8]
__device__ __forceinline__ void acc8(float* a, uint4 h, float w){
  unsigned int u[4] = {h.x, h.y, h.z, h.w};
#pragma unroll
  for (int i=0;i<4;++i){
    a[2*i]   += w * bf2f((unsigned short)(u[i] & 0xffffu));
    a[2*i+1] += w * bf2f((unsigned short)(u[i] >> 16));
  }
}

// ---------------- prep: pack weights (gate-interleaved cols + Chebyshev fold) ----
__global__ void k_prep(const float* __restrict__ Wx, const float* __restrict__ Wh,
                       const float* __restrict__ bx, const float* __restrict__ bh,
                       const float* __restrict__ bg, const float* __restrict__ W1,
                       const float* __restrict__ b1, const float* __restrict__ W2,
                       unsigned short* __restrict__ Bct, float* __restrict__ btot,
                       unsigned short* __restrict__ W1t, float* __restrict__ b1p,
                       float* __restrict__ W2p)
{
  int idx = blockIdx.x*256 + threadIdx.x;
  if (idx < N_COL*K_TOT){
    int cc = idx / K_TOT, k = idx - cc*K_TOT;
    int g = (cc>>4)&3, d = (cc&15) + ((cc>>6)<<4);
    float v;
    if (k < 384){
      int kt = k >> 7, j = k & 127;
      const float* Wg = Wh + (size_t)g*3*128*128;
      if (kt == 0)      v = Wg[(size_t)j*128 + d] - Wg[(size_t)(256+j)*128 + d];
      else if (kt == 1) v = Wg[(size_t)(128+j)*128 + d];
      else              v = 2.f*Wg[(size_t)(256+j)*128 + d];
    } else {
      int kk = k - 384; int kt = kk >> 6, j = kk & 63;
      const float* Wg = Wx + (size_t)g*3*64*128;
      if (kt == 0)      v = Wg[(size_t)j*128 + d] - Wg[(size_t)(128+j)*128 + d];
      else if (kt == 1) v = Wg[(size_t)(64+j)*128 + d];
      else              v = 2.f*Wg[(size_t)(128+j)*128 + d];
    }
    Bct[(size_t)cc*K_TOT + k] = f2bf(v);
  }
  if (idx < N_COL) btot[idx] = bx[idx] + bh[idx] + bg[idx];
  if (idx < HID_P*D_H){ int c = idx >> 7, k = idx & 127;
    W1t[idx] = (c < N_HID) ? f2bf(W1[k*N_HID + c]) : (unsigned short)0; }
  if (idx < HID_P) b1p[idx] = (idx < N_HID) ? b1[idx] : 0.f;
  if (idx < HID_P*2){ int c = idx >> 1, j = idx & 1; W2p[idx] = (c < N_HID) ? W2[c*2 + j] : 0.f; }
}

// ---------------- x conversion: H -> Xtr [n][d][12] + Axt x-planes ----------------
__global__ void k_xprep(const float* __restrict__ H, unsigned short* __restrict__ Xtr,
                        unsigned short* __restrict__ Axt){
  int idx = blockIdx.x*256 + threadIdx.x;    // (n,d)
  if (idx >= N_PAD*64) return;
  int n = idx >> 6, d = idx & 63;
  union { unsigned short u[12]; uint2 q[3]; } pk;
  if (n < N_NODE){
#pragma unroll
    for (int t=0;t<12;++t) pk.u[t] = f2bf(H[((size_t)t*N_NODE + n)*64 + d]);
  } else {
#pragma unroll
    for (int t=0;t<12;++t) pk.u[t] = 0;
  }
  uint2* xp = (uint2*)(Xtr + (size_t)idx*12);
  xp[0]=pk.q[0]; xp[1]=pk.q[1]; xp[2]=pk.q[2];
#pragma unroll
  for (int t=0;t<12;++t) Axt[((size_t)t*N_PAD + n)*AXC + d] = pk.u[t];
  if (n >= N_NODE){
#pragma unroll
    for (int t=0;t<12;++t){
      Axt[((size_t)t*N_PAD + n)*AXC + 64 + d]  = 0;
      Axt[((size_t)t*N_PAD + n)*AXC + 128 + d] = 0;
    }
  }
}

// ---------------- graph preprocessing ----------------
__global__ void k_deg(const int* __restrict__ ei, int* __restrict__ dsrc, int* __restrict__ ddst){
  int e = blockIdx.x*256 + threadIdx.x;
  if (e < N_E){
    atomicAdd(&dsrc[ei[e]], 1);
    atomicAdd(&ddst[ei[N_E + e]], 1);
  }
}
__global__ void k_dinv(const int* __restrict__ dsrc, float* __restrict__ dinv){
  int n = blockIdx.x*256 + threadIdx.x;
  if (n < N_P2) dinv[n] = (dsrc[n] > 0) ? rsqrtf((float)dsrc[n]) : 0.f;
}
__global__ void k_scan1(const int* __restrict__ in, int* __restrict__ outp, int* __restrict__ part){
  __shared__ int sm[256];
  int tid = threadIdx.x;
  int i = blockIdx.x*256 + tid;
  int v = in[i];
  int x = v;
  sm[tid] = x; __syncthreads();
  for (int off=1; off<256; off<<=1){
    int y = (tid >= off) ? sm[tid-off] : 0;
    __syncthreads();
    x += y; sm[tid] = x; __syncthreads();
  }
  outp[i] = x - v;
  if (tid == 255) part[blockIdx.x] = x;
}
__global__ void k_scan2(int* __restrict__ part, int nblk){
  __shared__ int sm[256];
  int tid = threadIdx.x;
  int v = (tid < nblk) ? part[tid] : 0;
  int x = v; sm[tid] = x; __syncthreads();
  for (int off=1; off<256; off<<=1){
    int y = (tid >= off) ? sm[tid-off] : 0;
    __syncthreads();
    x += y; sm[tid] = x; __syncthreads();
  }
  if (tid < nblk) part[tid] = x - v;
}
__global__ void k_scan3(const int* __restrict__ outp, const int* __restrict__ part, int* __restrict__ offs){
  int i = blockIdx.x*256 + threadIdx.x;
  offs[i] = outp[i] + part[blockIdx.x];
}
__global__ void k_csr(const int* __restrict__ ei, const float* __restrict__ dinv,
                      const int* __restrict__ offs, int* __restrict__ cursor,
                      int2* __restrict__ cedge){
  int e = blockIdx.x*256 + threadIdx.x;
  if (e < N_E){
    int s = ei[e], d = ei[N_E + e];
    int pos = atomicAdd(&cursor[d], 1);
    float w = -dinv[s]*dinv[d];
    cedge[offs[d] + pos] = make_int2(s, __float_as_int(w));
  }
}

// ---------------- x-side spmm, all 12 t at once via [n][d][t] gathers -----------
__global__ void k_xspmm1(const unsigned short* __restrict__ Xtr, unsigned short* __restrict__ Axt,
                         unsigned short* __restrict__ U1tr,
                         const int* __restrict__ offs, const int2* __restrict__ cedge){
  int n = blockIdx.x*4 + (threadIdx.x >> 6);
  int l = threadIdx.x & 63;
  if (n >= N_NODE) return;
  int beg = offs[n], end = offs[n+1];
  float a[12];
#pragma unroll
  for (int t=0;t<12;++t) a[t] = 0.f;
  for (int q = beg; q < end; q += 3){
    int2 e0 = cedge[q];
    int2 e1 = (q+1 < end) ? cedge[q+1] : make_int2(0,0);
    int2 e2 = (q+2 < end) ? cedge[q+2] : make_int2(0,0);
    const uint2* r0 = (const uint2*)(Xtr + ((size_t)e0.x*64 + l)*12);
    const uint2* r1 = (const uint2*)(Xtr + ((size_t)e1.x*64 + l)*12);
    const uint2* r2 = (const uint2*)(Xtr + ((size_t)e2.x*64 + l)*12);
    uint2 p00=r0[0], p01=r0[1], p02=r0[2];
    uint2 p10=r1[0], p11=r1[1], p12=r1[2];
    uint2 p20=r2[0], p21=r2[1], p22=r2[2];
    acc12(a, p00, p01, p02, __int_as_float(e0.y));
    acc12(a, p10, p11, p12, __int_as_float(e1.y));
    acc12(a, p20, p21, p22, __int_as_float(e2.y));
  }
  union { unsigned short u[12]; uint2 qq[3]; } pk;
#pragma unroll
  for (int t=0;t<12;++t){
    unsigned short b = f2bf(a[t]);
    pk.u[t] = b;
    Axt[((size_t)t*N_PAD + n)*AXC + 64 + l] = b;
  }
  uint2* op = (uint2*)(U1tr + ((size_t)n*64 + l)*12);
  op[0]=pk.qq[0]; op[1]=pk.qq[1]; op[2]=pk.qq[2];
}
__global__ void k_xspmm2(const unsigned short* __restrict__ U1tr, unsigned short* __restrict__ Axt,
                         const int* __restrict__ offs, const int2* __restrict__ cedge){
  int n = blockIdx.x*4 + (threadIdx.x >> 6);
  int l = threadIdx.x & 63;
  if (n >= N_NODE) return;
  int beg = offs[n], end = offs[n+1];
  float a[12];
#pragma unroll
  for (int t=0;t<12;++t) a[t] = 0.f;
  for (int q = beg; q < end; q += 3){
    int2 e0 = cedge[q];
    int2 e1 = (q+1 < end) ? cedge[q+1] : make_int2(0,0);
    int2 e2 = (q+2 < end) ? cedge[q+2] : make_int2(0,0);
    const uint2* r0 = (const uint2*)(U1tr + ((size_t)e0.x*64 + l)*12);
    const uint2* r1 = (const uint2*)(U1tr + ((size_t)e1.x*64 + l)*12);
    const uint2* r2 = (const uint2*)(U1tr + ((size_t)e2.x*64 + l)*12);
    uint2 p00=r0[0], p01=r0[1], p02=r0[2];
    uint2 p10=r1[0], p11=r1[1], p12=r1[2];
    uint2 p20=r2[0], p21=r2[1], p22=r2[2];
    acc12(a, p00, p01, p02, __int_as_float(e0.y));
    acc12(a, p10, p11, p12, __int_as_float(e1.y));
    acc12(a, p20, p21, p22, __int_as_float(e2.y));
  }
#pragma unroll
  for (int t=0;t<12;++t)
    Axt[((size_t)t*N_PAD + n)*AXC + 128 + l] = f2bf(a[t]);
}

// ---------------- per-step h-side spmm: 4 edges/wave x 16B/lane ----------------
// lane = (sub = l>>4) edge slot, (fl = l&15) 8-feature block; 8 edges in flight.
__global__ void k_spmm1(const unsigned short* __restrict__ Hc, unsigned short* __restrict__ U,
                        const int* __restrict__ offs, const int2* __restrict__ cedge){
  int n = blockIdx.x*4 + (threadIdx.x >> 6);
  int l = threadIdx.x & 63;
  if (n >= N_NODE) return;
  int sub = l >> 4, fl = l & 15;
  int beg = offs[n], end = offs[n+1];
  float a[8];
#pragma unroll
  for (int j=0;j<8;++j) a[j] = 0.f;
  for (int q = beg; q < end; q += 8){
    int i0 = q + sub, i1 = q + 4 + sub;
    int2 e0 = (i0 < end) ? cedge[i0] : make_int2(0,0);
    int2 e1 = (i1 < end) ? cedge[i1] : make_int2(0,0);
    uint4 h0 = *(const uint4*)(Hc + (size_t)e0.x*128 + fl*8);
    uint4 h1 = *(const uint4*)(Hc + (size_t)e1.x*128 + fl*8);
    acc8(a, h0, __int_as_float(e0.y));
    acc8(a, h1, __int_as_float(e1.y));
  }
#pragma unroll
  for (int j=0;j<8;++j){
    a[j] += __shfl_xor(a[j], 16);
    a[j] += __shfl_xor(a[j], 32);
  }
  if (sub == 0){
    unsigned short o[8];
#pragma unroll
    for (int j=0;j<8;++j) o[j] = f2bf(a[j]);
    *(uint4*)(U + (size_t)n*256 + fl*8) = *(const uint4*)o;
  }
}
__global__ void k_spmm2(unsigned short* __restrict__ U,
                        const int* __restrict__ offs, const int2* __restrict__ cedge){
  int n = blockIdx.x*4 + (threadIdx.x >> 6);
  int l = threadIdx.x & 63;
  if (n >= N_NODE) return;
  int sub = l >> 4, fl = l & 15;
  int beg = offs[n], end = offs[n+1];
  float a[8];
#pragma unroll
  for (int j=0;j<8;++j) a[j] = 0.f;
  for (int q = beg; q < end; q += 8){
    int i0 = q + sub, i1 = q + 4 + sub;
    int2 e0 = (i0 < end) ? cedge[i0] : make_int2(0,0);
    int2 e1 = (i1 < end) ? cedge[i1] : make_int2(0,0);
    uint4 h0 = *(const uint4*)(U + (size_t)e0.x*256 + fl*8);
    uint4 h1 = *(const uint4*)(U + (size_t)e1.x*256 + fl*8);
    acc8(a, h0, __int_as_float(e0.y));
    acc8(a, h1, __int_as_float(e1.y));
  }
#pragma unroll
  for (int j=0;j<8;++j){
    a[j] += __shfl_xor(a[j], 16);
    a[j] += __shfl_xor(a[j], 32);
  }
  if (sub == 0){
    unsigned short o[8];
#pragma unroll
    for (int j=0;j<8;++j) o[j] = f2bf(a[j]);
    *(uint4*)(U + (size_t)n*256 + 128 + fl*8) = *(const uint4*)o;
  }
}

// ---------------- fused GEMM + LSTM gates ----------------
__global__ __launch_bounds__(256,2) void k_gemm(
    const unsigned short* __restrict__ Hc, const unsigned short* __restrict__ U,
    const unsigned short* __restrict__ Axt,
    const unsigned short* __restrict__ Bct, const float* __restrict__ btot,
    const float* __restrict__ wc, float* __restrict__ c, unsigned short* __restrict__ Hn)
{
  __shared__ __align__(16) unsigned short As[128*64];
  __shared__ __align__(16) unsigned short Bs[128*64];
  int tid = threadIdx.x;
  int w = tid >> 6, l = tid & 63;
  const int NWG = 1564, q8 = NWG >> 3, r8 = NWG & 7;
  int L = blockIdx.y*4 + blockIdx.x;
  int xcd = L & 7, li = L >> 3;
  int W = (xcd < r8 ? xcd*(q8+1) : r8*(q8+1) + (xcd-r8)*q8) + li;
  int bx = W & 3, by = W >> 2;
  int n0 = bx * 128;
  int m0 = by * 128;
  const f32x4 vzero = {0.f,0.f,0.f,0.f};
  f32x4 acc[4][4];
#pragma unroll
  for (int i=0;i<4;++i)
#pragma unroll
    for (int j=0;j<4;++j) acc[i][j] = vzero;
  int wr = w >> 1, wn = w & 1;
  for (int it=0; it<9; ++it){
    const unsigned short* Ab; int astr, acol;
    if (it < 2)      { Ab = Hc;  astr = 128; acol = it*64; }
    else if (it < 6) { Ab = U;   astr = 256; acol = (it-2)*64; }
    else             { Ab = Axt; astr = AXC; acol = (it-6)*64; }
    if (it) __syncthreads();
#pragma unroll
    for (int i=0;i<4;++i){
      int rr = w*32 + i*8;
      int row = rr + (l>>3);
      gload16(Ab  + (size_t)(m0+row)*astr + acol + (l&7)*8, (void*)(As + rr*64));
      gload16(Bct + (size_t)(n0+row)*K_TOT + it*64 + (l&7)*8, (void*)(Bs + rr*64));
    }
    __syncthreads();
#pragma unroll
    for (int kk=0; kk<2; ++kk){
      bf16x8 af[4], bfv[4];
#pragma unroll
      for (int i=0;i<4;++i) af[i]  = *(const bf16x8*)(As + (wr*64 + i*16 + (l&15))*64 + kk*32 + (l>>4)*8);
#pragma unroll
      for (int j=0;j<4;++j) bfv[j] = *(const bf16x8*)(Bs + (wn*64 + j*16 + (l&15))*64 + kk*32 + (l>>4)*8);
#pragma unroll
      for (int i=0;i<4;++i)
#pragma unroll
        for (int j=0;j<4;++j)
          acc[i][j] = __builtin_amdgcn_mfma_f32_16x16x32_bf16(af[i], bfv[j], acc[i][j], 0,0,0);
    }
  }
  int dd = (((bx<<1) + wn) << 4) | (l & 15);
  float b_i = btot[dd], b_f = btot[128+dd], b_t = btot[256+dd], b_o = btot[384+dd];
  float wci = wc[dd], wcf = wc[128+dd], wco = wc[256+dd];
#pragma unroll
  for (int i=0;i<4;++i){
    int row0 = m0 + wr*64 + i*16 + (l>>4)*4;
#pragma unroll
    for (int r=0;r<4;++r){
      int row = row0 + r;
      float co = c[(size_t)row*128 + dd];
      float gi = sigf(acc[i][0][r] + b_i + wci*co);
      float gf = sigf(acc[i][1][r] + b_f + wcf*co);
      float tt = ftanh(acc[i][2][r] + b_t);
      float cn = gf*co + gi*tt;
      float go = sigf(acc[i][3][r] + b_o + wco*cn);
      float h = go * ftanh(cn);
      c[(size_t)row*128 + dd] = cn;
      Hn[(size_t)row*128 + dd] = f2bf(h);
    }
  }
}

// ---------------- tanh + LN + MLP + sigmoid + transpose (per step) ----------------
__global__ __launch_bounds__(256,2) void k_lnmlp(const unsigned short* __restrict__ Hn,
                        const unsigned short* __restrict__ W1t, const float* __restrict__ b1p,
                        const float* __restrict__ W2p, const float* __restrict__ b2,
                        const float* __restrict__ gam, const float* __restrict__ bet,
                        float* __restrict__ out, int t)
{
  __shared__ __align__(16) unsigned short xn[64*128];
  __shared__ __align__(16) unsigned short w1s[HID_P*128];
  __shared__ float w2s[HID_P*2];
  __shared__ float b1s[HID_P];
  __shared__ float b2s[2];
  int tid = threadIdx.x;
  for (int i = tid; i < HID_P*128/8; i += 256) ((int4*)w1s)[i] = ((const int4*)W1t)[i];
  if (tid < HID_P*2) w2s[tid] = W2p[tid];
  if (tid < HID_P)   b1s[tid] = b1p[tid];
  if (tid < 2)       b2s[tid] = b2[tid];
  int n0 = blockIdx.x*64;
  int row = tid >> 2, part = tid & 3;
  int n = n0 + row;
  float vals[32];
  float s = 0.f, ss = 0.f;
  if (n < N_NODE){
    const unsigned short* hp = Hn + (size_t)n*128 + part*32;
#pragma unroll
    for (int k=0;k<32;++k){
      float x = ftanh(bf2f(hp[k]));
      vals[k] = x; s += x; ss += x*x;
    }
  } else {
#pragma unroll
    for (int k=0;k<32;++k) vals[k] = 0.f;
  }
  s  += __shfl_xor(s,1);  s  += __shfl_xor(s,2);
  ss += __shfl_xor(ss,1); ss += __shfl_xor(ss,2);
  float mu = s * (1.f/128.f);
  float var = ss * (1.f/128.f) - mu*mu;
  float inv = rsqrtf(fmaxf(var, 0.f) + 1e-5f);
#pragma unroll
  for (int k=0;k<32;++k){
    int d = part*32 + k;
    xn[row*128 + d] = f2bf((vals[k]-mu)*inv*gam[d] + bet[d]);
  }
  __syncthreads();
  int w = tid >> 6, l = tid & 63;
  const f32x4 vzero = {0.f,0.f,0.f,0.f};
  f32x4 acc[5];
#pragma unroll
  for (int tj=0;tj<5;++tj) acc[tj] = vzero;
#pragma unroll
  for (int kk=0;kk<4;++kk){
    bf16x8 a = *(const bf16x8*)(xn + (w*16 + (l&15))*128 + kk*32 + (l>>4)*8);
#pragma unroll
    for (int tj=0;tj<5;++tj){
      bf16x8 b = *(const bf16x8*)(w1s + (tj*16 + (l&15))*128 + kk*32 + (l>>4)*8);
      acc[tj] = __builtin_amdgcn_mfma_f32_16x16x32_bf16(a, b, acc[tj], 0,0,0);
    }
  }
#pragma unroll
  for (int r=0;r<4;++r){
    int rn = n0 + w*16 + (l>>4)*4 + r;
    float p0 = 0.f, p1 = 0.f;
#pragma unroll
    for (int tj=0;tj<5;++tj){
      int col = tj*16 + (l&15);
      float hv = fmaxf(acc[tj][r] + b1s[col], 0.f);
      p0 += hv * w2s[col*2];
      p1 += hv * w2s[col*2+1];
    }
    p0 += __shfl_xor(p0,1); p0 += __shfl_xor(p0,2); p0 += __shfl_xor(p0,4); p0 += __shfl_xor(p0,8);
    p1 += __shfl_xor(p1,1); p1 += __shfl_xor(p1,2); p1 += __shfl_xor(p1,4); p1 += __shfl_xor(p1,8);
    if ((l & 15) == 0 && rn < N_NODE){
      float* op = out + (size_t)rn*24 + t;   // out[n][c][s], C=2, S=12
      op[0]  = sigf(p0 + b2s[0]);
      op[12] = sigf(p1 + b2s[1]);
    }
  }
}

extern "C" void kernel_launch(void* const* d_in, const int* in_sizes, int n_in,
                              void* d_out, int out_size, void* d_ws, size_t ws_size,
                              hipStream_t stream)
{
  const float* H   = (const float*)d_in[0];
  const int*   ei  = (const int*)d_in[1];
  const float* Wx  = (const float*)d_in[2];
  const float* bx  = (const float*)d_in[3];
  const float* Wh  = (const float*)d_in[4];
  const float* bh  = (const float*)d_in[5];
  const float* bg  = (const float*)d_in[6];
  const float* wc  = (const float*)d_in[7];
  const float* gam = (const float*)d_in[8];
  const float* bet = (const float*)d_in[9];
  const float* W1  = (const float*)d_in[10];
  const float* b1  = (const float*)d_in[11];
  const float* W2  = (const float*)d_in[12];
  const float* b2  = (const float*)d_in[13];
  float* out = (float*)d_out;
  (void)in_sizes; (void)n_in; (void)out_size; (void)ws_size;

  char* p = (char*)d_ws;
  auto alloc = [&](size_t bytes)->char*{ char* r = p; p += (bytes + 255) & ~(size_t)255; return r; };
  // ---- zeroed region (one memset) ----
  char* zbase = p;
  float*          c_st  = (float*)alloc((size_t)N_PAD*128*4);
  unsigned short* Hbuf0 = (unsigned short*)alloc((size_t)N_PAD*128*2);
  int* dsrc   = (int*)alloc((size_t)N_P2*4);
  int* ddst   = (int*)alloc((size_t)N_P2*4);
  int* cursor = (int*)alloc((size_t)N_P2*4);
  size_t zbytes = (size_t)(p - zbase);
  // ---- rest ----
  unsigned short* Hbuf1 = (unsigned short*)alloc((size_t)N_PAD*128*2);
  unsigned short* Ubuf  = (unsigned short*)alloc((size_t)N_PAD*256*2);
  unsigned short* Xtr   = (unsigned short*)alloc((size_t)N_PAD*64*12*2);
  unsigned short* U1tr  = (unsigned short*)alloc((size_t)N_PAD*64*12*2);
  unsigned short* Axt   = (unsigned short*)alloc((size_t)S_DIM*N_PAD*AXC*2);
  unsigned short* Bct   = (unsigned short*)alloc((size_t)N_COL*K_TOT*2);
  float*          btot  = (float*)alloc(N_COL*4);
  unsigned short* W1t   = (unsigned short*)alloc(HID_P*128*2);
  float*          b1p   = (float*)alloc(HID_P*4);
  float*          W2p   = (float*)alloc(HID_P*2*4);
  float*          dinv  = (float*)alloc((size_t)N_P2*4);
  int*            offs  = (int*)alloc((size_t)(N_P2+256)*4);
  int*            outp  = (int*)alloc((size_t)N_P2*4);
  int*            partb = (int*)alloc(256*4);
  int2*           cedge = (int2*)alloc((size_t)N_E*8);

  hipMemsetAsync(zbase, 0, zbytes, stream);
  k_prep<<<(N_COL*K_TOT + 255)/256, 256, 0, stream>>>(Wx, Wh, bx, bh, bg, W1, b1, W2,
                                                      Bct, btot, W1t, b1p, W2p);
  k_xprep<<<(N_PAD*64 + 255)/256, 256, 0, stream>>>(H, Xtr, Axt);
  k_deg<<<(N_E + 255)/256, 256, 0, stream>>>(ei, dsrc, ddst);
  k_dinv<<<N_P2/256, 256, 0, stream>>>(dsrc, dinv);
  k_scan1<<<N_P2/256, 256, 0, stream>>>(ddst, outp, partb);
  k_scan2<<<1, 256, 0, stream>>>(partb, N_P2/256);
  k_scan3<<<N_P2/256, 256, 0, stream>>>(outp, partb, offs);
  k_csr<<<(N_E + 255)/256, 256, 0, stream>>>(ei, dinv, offs, cursor, cedge);
  k_xspmm1<<<N_NODE/4, 256, 0, stream>>>(Xtr, Axt, U1tr, offs, cedge);
  k_xspmm2<<<N_NODE/4, 256, 0, stream>>>(U1tr, Axt, offs, cedge);

  for (int t = 0; t < S_DIM; ++t){
    unsigned short* Hc = (t & 1) ? Hbuf1 : Hbuf0;
    unsigned short* Hn = (t & 1) ? Hbuf0 : Hbuf1;
    k_spmm1<<<N_NODE/4, 256, 0, stream>>>(Hc, Ubuf, offs, cedge);
    k_spmm2<<<N_NODE/4, 256, 0, stream>>>(Ubuf, offs, cedge);
    k_gemm<<<dim3(4, N_PAD/128), 256, 0, stream>>>(Hc, Ubuf,
        Axt + (size_t)t*N_PAD*AXC, Bct, btot, wc, c_st, Hn);
    k_lnmlp<<<N_PAD/64, 256, 0, stream>>>(Hn, W1t, b1p, W2p, b2, gam, bet, out, t);
  }
}